// Round 17
// baseline (363.759 us; speedup 1.0000x reference)
//
#include <hip/hip_runtime.h>
#include <hip/hip_bf16.h>
#include <math.h>

#define S_LEN 2048
#define D_DIM 2048
#define NH 32
#define HD 64
#define CS 256
#define NCH 8

typedef __attribute__((ext_vector_type(8))) short bf16x8;
typedef __attribute__((ext_vector_type(4))) short bf16x4;
typedef __attribute__((ext_vector_type(4))) float f32x4;

__device__ __forceinline__ unsigned short f2bf(float f) {
  unsigned int u = __builtin_bit_cast(unsigned int, f);
  unsigned int r = (u + 0x7fffu + ((u >> 16) & 1u)) >> 16;
  return (unsigned short)r;
}
__device__ __forceinline__ float bf2f(unsigned short b) {
  unsigned int u = ((unsigned int)b) << 16;
  return __builtin_bit_cast(float, u);
}

__device__ __forceinline__ f32x4 mfma16(bf16x4 a, bf16x4 b, f32x4 c) {
#if __has_builtin(__builtin_amdgcn_mfma_f32_16x16x16_bf16)
  return __builtin_amdgcn_mfma_f32_16x16x16_bf16(a, b, c, 0, 0, 0);
#elif __has_builtin(__builtin_amdgcn_mfma_f32_16x16x16bf16_1k)
  return __builtin_amdgcn_mfma_f32_16x16x16bf16_1k(a, b, c, 0, 0, 0);
#else
  asm("v_mfma_f32_16x16x16_bf16 %0, %1, %2, %0" : "+v"(c) : "v"(a), "v"(b));
  return c;
#endif
}

__device__ __forceinline__ void gload16(const void* gp, void* lp) {
  __builtin_amdgcn_global_load_lds(
      (const __attribute__((address_space(1))) unsigned int*)gp,
      (__attribute__((address_space(3))) unsigned int*)lp, 16, 0, 0);
}

// ---------------------------------------------------------------------------
// RoPE cos/sin table: rope_tab[s][d] = (cosf(s*inv(d)), sinf(s*inv(d))),
// d in [0,32). Same float expressions as the reference rope.
// ---------------------------------------------------------------------------
__global__ __launch_bounds__(256) void rope_tab_k(float2* __restrict__ tab) {
  int idx = blockIdx.x * 256 + threadIdx.x;
  if (idx >= S_LEN * 32) return;
  int d = idx & 31;
  int s = idx >> 5;
  float inv = 1.0f / powf(10000.0f, (float)d * (1.0f / 32.0f));
  float fr = (float)s * inv;
  tab[idx] = make_float2(cosf(fr), sinf(fr));
}

// ---------------------------------------------------------------------------
// Fused QKVG GEMM, 128x128 tile (4 waves x 64x64), BK=64, 32KB LDS.
// EXACT R12/R16 form (125us, VGPR 68, no spill). RoPE lives in the consumers.
// ---------------------------------------------------------------------------
struct QKVG {
  const unsigned short* xh;
  const unsigned short* xl;
  const unsigned short* wh[4];
  const unsigned short* wl[4];
  float* C[4];
  int np[4];
};

__global__ __launch_bounds__(256) void gemm_qkvg(QKVG g) {
  __shared__ __align__(16) unsigned short Als[128 * 64];
  __shared__ __align__(16) unsigned short Bls[128 * 64];
  const int tid = threadIdx.x;
  const int wid = tid >> 6, lane = tid & 63;
  const int l15 = lane & 15, l4 = lane >> 4;
  const int wr = wid >> 1, wc = wid & 1;
  const int K = D_DIM, N = D_DIM;

  const int bid = blockIdx.x;
  const int xcd = bid & 7;
  const int local = bid >> 3;
  const int c = local >> 6;
  const int idx = local & 63;
  const int out = (xcd & 1) + 2 * c;
  const int grp = xcd >> 1;
  const int row0 = (idx >> 2) << 7;
  const int col0 = ((grp << 2) + (idx & 3)) << 7;

  f32x4 acc[4][4];
#pragma unroll
  for (int m = 0; m < 4; ++m)
#pragma unroll
    for (int n = 0; n < 4; ++n) acc[m][n] = (f32x4){0.f, 0.f, 0.f, 0.f};

  const int np = g.np[out];
  for (int p = 0; p < np; ++p) {
    const unsigned short* Ap = (p == 2) ? g.xl : g.xh;
    const unsigned short* Bp = (p == 1) ? g.wl[out] : g.wh[out];
    for (int kt = 0; kt < K; kt += 64) {
      __syncthreads();
#pragma unroll
      for (int i = 0; i < 4; ++i) {
        const int Lb = i * 4096 + wid * 1024;
        const int L = Lb + lane * 16;
        const int row = L >> 7;
        const int s = (L >> 4) & 7;
        const int cofs = (s ^ (row & 7)) << 3;
        gload16(Ap + (size_t)(row0 + row) * K + kt + cofs, (char*)Als + Lb);
        gload16(Bp + (size_t)(col0 + row) * K + kt + cofs, (char*)Bls + Lb);
      }
      asm volatile("s_waitcnt vmcnt(0)" ::: "memory");
      __syncthreads();
#pragma unroll
      for (int ks = 0; ks < 2; ++ks) {
        bf16x8 af[4], bfr[4];
#pragma unroll
        for (int m = 0; m < 4; ++m) {
          int row = wr * 64 + m * 16 + l15;
          int s = (ks * 4 + l4) ^ (row & 7);
          af[m] = *reinterpret_cast<const bf16x8*>(&Als[row * 64 + s * 8]);
        }
#pragma unroll
        for (int n = 0; n < 4; ++n) {
          int col = wc * 64 + n * 16 + l15;
          int s = (ks * 4 + l4) ^ (col & 7);
          bfr[n] = *reinterpret_cast<const bf16x8*>(&Bls[col * 64 + s * 8]);
        }
#pragma unroll
        for (int m = 0; m < 4; ++m)
#pragma unroll
          for (int n = 0; n < 4; ++n)
            acc[m][n] = __builtin_amdgcn_mfma_f32_16x16x32_bf16(af[m], bfr[n], acc[m][n], 0, 0, 0);
      }
    }
  }

  float* C = g.C[out];
#pragma unroll
  for (int m = 0; m < 4; ++m)
#pragma unroll
    for (int n = 0; n < 4; ++n)
#pragma unroll
      for (int r = 0; r < 4; ++r)
        C[(size_t)(row0 + wr * 64 + m * 16 + l4 * 4 + r) * N + col0 + wc * 64 + n * 16 + l15] =
            acc[m][n][r];
}

// ---------------------------------------------------------------------------
// bf16 MFMA GEMM 64x128 (out-projection).
// ---------------------------------------------------------------------------
struct G3 {
  const unsigned short* A[3];
  const unsigned short* B[3];
  int np;
};

__global__ __launch_bounds__(256) void gemm_bt(G3 g, float* __restrict__ C,
                                               int M, int N, int K) {
  __shared__ __align__(16) unsigned short Als[64 * 64];
  __shared__ __align__(16) unsigned short Bls[128 * 64];
  const int tid = threadIdx.x;
  const int wid = tid >> 6, lane = tid & 63;
  const int l15 = lane & 15, l4 = lane >> 4;
  const int wr = wid >> 1, wc = wid & 1;
  const int nbx = N >> 7;
  int bid = blockIdx.x;
  const int nwg = gridDim.x;
  if ((nwg & 7) == 0) {
    int q = nwg >> 3;
    bid = (bid & 7) * q + (bid >> 3);
  }
  const int row0 = (bid / nbx) << 6;
  const int col0 = (bid % nbx) << 7;

  f32x4 acc[2][4];
#pragma unroll
  for (int m = 0; m < 2; ++m)
#pragma unroll
    for (int n = 0; n < 4; ++n) acc[m][n] = (f32x4){0.f, 0.f, 0.f, 0.f};

  for (int p = 0; p < g.np; ++p) {
    const unsigned short* Ap = g.A[p];
    const unsigned short* Bp = g.B[p];
    for (int kt = 0; kt < K; kt += 64) {
      __syncthreads();
#pragma unroll
      for (int i = 0; i < 2; ++i) {
        const int Lb = i * 4096 + wid * 1024;
        const int L = Lb + lane * 16;
        const int row = L >> 7;
        const int s = (L >> 4) & 7;
        const int cofs = (s ^ (row & 7)) << 3;
        gload16(Ap + (size_t)(row0 + row) * K + kt + cofs, (char*)Als + Lb);
      }
#pragma unroll
      for (int i = 0; i < 4; ++i) {
        const int Lb = i * 4096 + wid * 1024;
        const int L = Lb + lane * 16;
        const int row = L >> 7;
        const int s = (L >> 4) & 7;
        const int cofs = (s ^ (row & 7)) << 3;
        gload16(Bp + (size_t)(col0 + row) * K + kt + cofs, (char*)Bls + Lb);
      }
      asm volatile("s_waitcnt vmcnt(0)" ::: "memory");
      __syncthreads();
#pragma unroll
      for (int ks = 0; ks < 2; ++ks) {
        bf16x8 af[2], bfr[4];
#pragma unroll
        for (int m = 0; m < 2; ++m) {
          int row = wr * 32 + m * 16 + l15;
          int s = (ks * 4 + l4) ^ (row & 7);
          af[m] = *reinterpret_cast<const bf16x8*>(&Als[row * 64 + s * 8]);
        }
#pragma unroll
        for (int n = 0; n < 4; ++n) {
          int col = wc * 64 + n * 16 + l15;
          int s = (ks * 4 + l4) ^ (col & 7);
          bfr[n] = *reinterpret_cast<const bf16x8*>(&Bls[col * 64 + s * 8]);
        }
#pragma unroll
        for (int m = 0; m < 2; ++m)
#pragma unroll
          for (int n = 0; n < 4; ++n)
            acc[m][n] = __builtin_amdgcn_mfma_f32_16x16x32_bf16(af[m], bfr[n], acc[m][n], 0, 0, 0);
      }
    }
  }

#pragma unroll
  for (int m = 0; m < 2; ++m)
#pragma unroll
    for (int n = 0; n < 4; ++n)
#pragma unroll
      for (int r = 0; r < 4; ++r)
        C[(size_t)(row0 + wr * 32 + m * 16 + l4 * 4 + r) * N + col0 + wc * 64 + n * 16 + l15] =
            acc[m][n][r];
}

// ---------------------------------------------------------------------------
// fp32 SGEMM for W' = Wg1 @ Wg2 (K=64), writing W'^T bf16 directly.
// ---------------------------------------------------------------------------
__global__ __launch_bounds__(256) void sgemm_f32T(const float* __restrict__ A,
                                                  const float* __restrict__ B,
                                                  unsigned short* __restrict__ CT,
                                                  int M, int N, int K) {
  __shared__ float As[8][128];
  __shared__ float Bs[8][128];
  const int tid = threadIdx.x;
  const int row0 = blockIdx.y * 128;
  const int col0 = blockIdx.x * 128;
  const int tm = (tid / 16) * 8;
  const int tn = (tid % 16) * 8;
  const int arow = tid >> 1;
  const int acol = (tid & 1) * 4;
  const int brow = tid >> 5;
  const int bcol = (tid & 31) * 4;

  float acc[8][8];
#pragma unroll
  for (int i = 0; i < 8; ++i)
#pragma unroll
    for (int j = 0; j < 8; ++j) acc[i][j] = 0.f;

  for (int k0 = 0; k0 < K; k0 += 8) {
    float4 av = make_float4(0.f, 0.f, 0.f, 0.f);
    if (row0 + arow < M) {
      int kb = k0 + acol;
      av = *reinterpret_cast<const float4*>(&A[(size_t)(row0 + arow) * K + kb]);
    }
    As[acol + 0][arow] = av.x;
    As[acol + 1][arow] = av.y;
    As[acol + 2][arow] = av.z;
    As[acol + 3][arow] = av.w;
    float4 bv = make_float4(0.f, 0.f, 0.f, 0.f);
    if (k0 + brow < K) {
      bv = *reinterpret_cast<const float4*>(&B[(size_t)(k0 + brow) * N + col0 + bcol]);
    }
    *reinterpret_cast<float4*>(&Bs[brow][bcol]) = bv;
    __syncthreads();
#pragma unroll
    for (int kk = 0; kk < 8; ++kk) {
      float a[8], b[8];
      *reinterpret_cast<float4*>(&a[0]) = *reinterpret_cast<const float4*>(&As[kk][tm]);
      *reinterpret_cast<float4*>(&a[4]) = *reinterpret_cast<const float4*>(&As[kk][tm + 4]);
      *reinterpret_cast<float4*>(&b[0]) = *reinterpret_cast<const float4*>(&Bs[kk][tn]);
      *reinterpret_cast<float4*>(&b[4]) = *reinterpret_cast<const float4*>(&Bs[kk][tn + 4]);
#pragma unroll
      for (int i = 0; i < 8; ++i)
#pragma unroll
        for (int j = 0; j < 8; ++j) acc[i][j] = fmaf(a[i], b[j], acc[i][j]);
    }
    __syncthreads();
  }
#pragma unroll
  for (int j = 0; j < 8; ++j) {
    const int n = col0 + tn + j;
    ushort4 u0 = make_ushort4(f2bf(acc[0][j]), f2bf(acc[1][j]), f2bf(acc[2][j]), f2bf(acc[3][j]));
    ushort4 u1 = make_ushort4(f2bf(acc[4][j]), f2bf(acc[5][j]), f2bf(acc[6][j]), f2bf(acc[7][j]));
    *reinterpret_cast<ushort4*>(&CT[(size_t)n * M + row0 + tm]) = u0;
    *reinterpret_cast<ushort4*>(&CT[(size_t)n * M + row0 + tm + 4]) = u1;
  }
}

// ---------------------------------------------------------------------------
// x fp32 -> xh, xl bf16 (hi/lo split).
// ---------------------------------------------------------------------------
__global__ __launch_bounds__(256) void repack_x_hl(const float* __restrict__ x,
                                                   unsigned short* __restrict__ xh,
                                                   unsigned short* __restrict__ xl) {
  int i = (blockIdx.x * 256 + threadIdx.x) * 4;
  float4 v = *reinterpret_cast<const float4*>(&x[i]);
  float f[4] = {v.x, v.y, v.z, v.w};
  unsigned short h[4], l[4];
#pragma unroll
  for (int j = 0; j < 4; ++j) {
    h[j] = f2bf(f[j]);
    l[j] = f2bf(f[j] - bf2f(h[j]));
  }
  *reinterpret_cast<ushort4*>(&xh[i]) = make_ushort4(h[0], h[1], h[2], h[3]);
  *reinterpret_cast<ushort4*>(&xl[i]) = make_ushort4(l[0], l[1], l[2], l[3]);
}

// ---------------------------------------------------------------------------
// Fused 4-weight transpose repack (Wq, Wk with lo; Wv, Wo hi-only).
// ---------------------------------------------------------------------------
struct RT4 {
  const float* W[4];
  unsigned short* hiT[4];
  unsigned short* loT[4];
  int has_lo[4];
};

__global__ __launch_bounds__(256) void repack_T4(RT4 a) {
  __shared__ float t[64][65];
  const int wsel = blockIdx.z;
  const float* W = a.W[wsel];
  unsigned short* hiT = a.hiT[wsel];
  unsigned short* loT = a.loT[wsel];
  const int has_lo = a.has_lo[wsel];
  const int k0 = blockIdx.y * 64, n0 = blockIdx.x * 64;
  const int tid = threadIdx.x;
  const int c = tid & 63, rr = tid >> 6;
#pragma unroll
  for (int r = 0; r < 16; ++r) {
    int kr = r * 4 + rr;
    t[kr][c] = W[(size_t)(k0 + kr) * D_DIM + n0 + c];
  }
  __syncthreads();
#pragma unroll
  for (int r = 0; r < 16; ++r) {
    int n = r * 4 + rr;
    float f = t[c][n];
    unsigned short hb = f2bf(f);
    hiT[(size_t)(n0 + n) * D_DIM + k0 + c] = hb;
    if (has_lo) loT[(size_t)(n0 + n) * D_DIM + k0 + c] = f2bf(f - bf2f(hb));
  }
}

// ---------------------------------------------------------------------------
// Chunk means of rope(k): rope applied on the fly (same t order -> identical
// sum as rope-then-mean). Pair element at hd^32 (bit 5 stays inside d field).
// ---------------------------------------------------------------------------
__global__ __launch_bounds__(256) void chunk_mean(const float* __restrict__ k,
                                                  const float2* __restrict__ rtab,
                                                  float* __restrict__ kg) {
  int idx = blockIdx.x * 256 + threadIdx.x;
  if (idx >= NCH * NH * HD) return;
  int c = idx / (NH * HD);
  int hd = idx % (NH * HD);
  const bool hi = (hd & 32) != 0;
  const int d31 = hd & 31;
  float sum = 0.f;
  for (int t = 0; t < CS; ++t) {
    float k1 = k[(size_t)(c * CS + t) * (NH * HD) + hd];
    float k2 = k[(size_t)(c * CS + t) * (NH * HD) + (hd ^ 32)];
    float2 cs = rtab[(c * CS + t) * 32 + d31];
    float val = hi ? (k1 * cs.x + k2 * cs.y) : (k1 * cs.x - k2 * cs.y);
    sum += val;
  }
  kg[idx] = sum * (1.0f / CS);
}

// ---------------------------------------------------------------------------
// Gate + top-3-past chunk selection (fp32). RoPE on q fused via shfl_xor(32):
// pair lanes d and d^32 hold the two rotation inputs.
// ---------------------------------------------------------------------------
__global__ __launch_bounds__(256) void gate_topk(const float* __restrict__ q,
                                                 const float2* __restrict__ rtab,
                                                 const float* __restrict__ kg,
                                                 int* __restrict__ amask) {
  int wid = threadIdx.x >> 6;
  int lane = threadIdx.x & 63;
  int s = blockIdx.x * 4 + wid;
  int h = blockIdx.y;
  int myc = s >> 8;
  float qraw = q[((size_t)s * NH + h) * HD + lane];
  float qpair = __shfl_xor(qraw, 32);
  float2 cs = rtab[s * 32 + (lane & 31)];
  float qd = (lane < 32) ? (qraw * cs.x - qpair * cs.y)
                         : (qraw * cs.x + qpair * cs.y);
  float g[NCH];
#pragma unroll
  for (int c = 0; c < NCH; ++c) {
    float p = qd * kg[((size_t)c * NH + h) * HD + lane];
#pragma unroll
    for (int off = 32; off; off >>= 1) p += __shfl_xor(p, off);
    g[c] = p;
  }
  int chosen = 0;
#pragma unroll
  for (int pick = 0; pick < 3; ++pick) {
    float best = -INFINITY;
    int bi = -1;
#pragma unroll
    for (int c = 0; c < NCH; ++c) {
      if (c < myc && !((chosen >> c) & 1) && g[c] > best) {
        best = g[c];
        bi = c;
      }
    }
    if (bi >= 0) chosen |= (1 << bi);
  }
  int mask = chosen | (1 << myc);
  if (lane == 0) amask[h * S_LEN + s] = mask;
}

// ---------------------------------------------------------------------------
// K,V fp32 [s][h][d] -> fragment-major bf16; RoPE applied to K from the LDS
// tile (both halves resident). V unchanged (no rope).
// ---------------------------------------------------------------------------
__global__ __launch_bounds__(256) void repack_kvf(const float* __restrict__ k,
                                                  const float* __restrict__ v,
                                                  const float2* __restrict__ rtab,
                                                  unsigned short* __restrict__ khf,
                                                  unsigned short* __restrict__ vhf) {
  __shared__ float tk[64][68];
  __shared__ float tv[64][68];
  const int t = blockIdx.x;
  const int h = blockIdx.y;
  const int tid = threadIdx.x;
  const int t0 = t * 64;
  {
    const int r = tid >> 2, c4 = (tid & 3) * 16;
    const float* sk = &k[((size_t)(t0 + r) * NH + h) * HD + c4];
    const float* sv = &v[((size_t)(t0 + r) * NH + h) * HD + c4];
#pragma unroll
    for (int qd = 0; qd < 4; ++qd) {
      *reinterpret_cast<float4*>(&tk[r][c4 + qd * 4]) =
          *reinterpret_cast<const float4*>(sk + qd * 4);
      *reinterpret_cast<float4*>(&tv[r][c4 + qd * 4]) =
          *reinterpret_cast<const float4*>(sv + qd * 4);
    }
  }
  __syncthreads();
  const int w = tid >> 6, l = tid & 63;
  const int l15 = l & 15, g = l >> 4;
  unsigned short* obk = khf + (((size_t)h * 32 + t) * 8) * 512;
  unsigned short* obv = vhf + (((size_t)h * 32 + t) * 8) * 512;
#pragma unroll
  for (int ff = 0; ff < 2; ++ff) {
    const int f = 2 * w + ff;
    {
      const int st = f >> 1, half = f & 1;
      const int row = st * 16 + l15;
      unsigned short uk[8];
#pragma unroll
      for (int i = 0; i < 8; ++i) {
        float2 cs = rtab[(t0 + row) * 32 + g * 8 + i];
        float k1 = tk[row][half * 32 + g * 8 + i];
        float k2 = tk[row][(half ^ 1) * 32 + g * 8 + i];
        float val = half ? (k1 * cs.x + k2 * cs.y) : (k1 * cs.x - k2 * cs.y);
        uk[i] = f2bf(val);
      }
      *reinterpret_cast<ushort4*>(obk + (size_t)f * 512 + l * 8) =
          make_ushort4(uk[0], uk[1], uk[2], uk[3]);
      *reinterpret_cast<ushort4*>(obk + (size_t)f * 512 + l * 8 + 4) =
          make_ushort4(uk[4], uk[5], uk[6], uk[7]);
    }
    {
      const int st = f >> 1, p = f & 1;
      unsigned short u[8];
#pragma unroll
      for (int e = 0; e < 8; ++e) {
        const int cb = 2 * p + (e >> 2);
        const int j = e & 3;
        u[e] = f2bf(tv[st * 16 + 4 * g + j][cb * 16 + l15]);
      }
      *reinterpret_cast<ushort4*>(obv + (size_t)f * 512 + l * 8) =
          make_ushort4(u[0], u[1], u[2], u[3]);
      *reinterpret_cast<ushort4*>(obv + (size_t)f * 512 + l * 8 + 4) =
          make_ushort4(u[4], u[5], u[6], u[7]);
    }
  }
}

// ---------------------------------------------------------------------------
// MFMA flash attention, split-K across 4 waves, fragment-major K/V loads.
// RoPE on q fused into the qf build (both head-dim halves already loaded).
// ---------------------------------------------------------------------------
__global__ __launch_bounds__(256) void attn_mfma(const float* __restrict__ q,
                                                 const float2* __restrict__ rtab,
                                                 const unsigned short* __restrict__ khf,
                                                 const unsigned short* __restrict__ vhf,
                                                 const int* __restrict__ amask,
                                                 float* __restrict__ o) {
  const int B = blockIdx.x;
  const int xcd = B & 7;
  const int jb = B >> 3;
  const int h = xcd + ((jb >> 7) << 3);
  const int s0 = (jb & 127) << 4;
  const int tid = threadIdx.x;
  const int wid = tid >> 6;
  const int lane = tid & 63;
  const int l15 = lane & 15, g = lane >> 4;
  const int myS = s0 + l15;
  const int myc = s0 >> 8;
  const int ktm = (s0 & (CS - 1)) >> 6;

  __shared__ float lm[4][16];
  __shared__ float ll[4][16];
  __shared__ float lacc[4][16][64];

  // Q B-frag: rope + 1/8 scale fold + bf16, from both head-dim halves
  const float* qrow = q + ((size_t)myS * NH + h) * HD;
  bf16x8 qf[2];
#pragma unroll
  for (int jj = 0; jj < 8; ++jj) {
    float2 cs = rtab[myS * 32 + g * 8 + jj];
    float q1 = qrow[g * 8 + jj];
    float q2 = qrow[32 + g * 8 + jj];
    qf[0][jj] = (short)f2bf((q1 * cs.x - q2 * cs.y) * 0.125f);
    qf[1][jj] = (short)f2bf((q2 * cs.x + q1 * cs.y) * 0.125f);
  }

  int mymask = amask[h * S_LEN + myS];
  int wmask = mymask;
  wmask |= __shfl_xor(wmask, 1);
  wmask |= __shfl_xor(wmask, 2);
  wmask |= __shfl_xor(wmask, 4);
  wmask |= __shfl_xor(wmask, 8);
  const int pmask = wmask & ~(1 << myc);
  const int ntot = (ktm + 1) + 4 * __popc(pmask);

  auto DEC = [&](int j) -> int {
    if (j <= ktm) return ((s0 & ~255) + (j << 6)) | (1 << 16);
    int jj = j - ktm - 1;
    int mm = pmask;
    int drop = jj >> 2;
    for (int b = 0; b < drop; ++b) mm &= mm - 1;
    int c = __ffs(mm) - 1;
    return ((c << 8) + ((jj & 3) << 6)) | (((mymask >> c) & 1) << 16);
  };

  const unsigned short* khh = khf + (((size_t)h * 32) << 12);
  const unsigned short* vhh = vhf + (((size_t)h * 32) << 12);

  bf16x8 kr[4][2];
  auto LOADK = [&](int t0) {
    const unsigned short* tb = khh + ((size_t)(t0 >> 6) << 12) + lane * 8;
#pragma unroll
    for (int f = 0; f < 8; ++f)
      kr[f >> 1][f & 1] = *reinterpret_cast<const bf16x8*>(tb + f * 512);
  };

  float m = -1e30f, lsum = 0.f;
  f32x4 accv[4];
#pragma unroll
  for (int i = 0; i < 4; ++i) accv[i] = (f32x4){0.f, 0.f, 0.f, 0.f};

  if (wid < ntot) LOADK(DEC(wid) & 0xFFFF);

#pragma unroll
  for (int i = 0; i < 8; ++i) {
    const int j = wid + (i << 2);
    if (j < ntot) {
      const int ent = DEC(j);
      const int t0 = ent & 0xFFFF;
      const bool lane_on = (ent >> 16) != 0;
      const bool diag = (j == ktm);

      const unsigned short* vtb = vhh + ((size_t)(t0 >> 6) << 12) + lane * 8;
      bf16x4 vb[4][4];
#pragma unroll
      for (int fp = 0; fp < 8; ++fp) {
        bf16x8 wv = *reinterpret_cast<const bf16x8*>(vtb + fp * 512);
        const int st = fp >> 1, pp = fp & 1;
#pragma unroll
        for (int jj = 0; jj < 4; ++jj) {
          vb[st][2 * pp][jj] = wv[jj];
          vb[st][2 * pp + 1][jj] = wv[4 + jj];
        }
      }

      float p[16];
      __builtin_amdgcn_s_setprio(1);
#pragma unroll
      for (int st = 0; st < 4; ++st) {
        f32x4 d = (f32x4){0.f, 0.f, 0.f, 0.f};
        d = __builtin_amdgcn_mfma_f32_16x16x32_bf16(kr[st][0], qf[0], d, 0, 0, 0);
        d = __builtin_amdgcn_mfma_f32_16x16x32_bf16(kr[st][1], qf[1], d, 0, 0, 0);
#pragma unroll
        for (int r = 0; r < 4; ++r) {
          bool ok = lane_on && (!diag || (t0 + st * 16 + 4 * g + r <= myS));
          p[st * 4 + r] = ok ? d[r] : -1e30f;
        }
      }
      __builtin_amdgcn_s_setprio(0);

      if (j + 4 < ntot) LOADK(DEC(j + 4) & 0xFFFF);

      float mt = -1e30f;
#pragma unroll
      for (int ii = 0; ii < 16; ++ii) mt = fmaxf(mt, p[ii]);
      mt = fmaxf(mt, __shfl_xor(mt, 16));
      mt = fmaxf(mt, __shfl_xor(mt, 32));

      const float mnew = fmaxf(m, mt);
      const float corr = __expf(m - mnew);
      float ps = 0.f;
#pragma unroll
      for (int ii = 0; ii < 16; ++ii) {
        float pv = (p[ii] > -1e29f) ? __expf(p[ii] - mnew) : 0.f;
        p[ii] = pv;
        ps += pv;
      }
      ps += __shfl_xor(ps, 16);
      ps += __shfl_xor(ps, 32);
      lsum = lsum * corr + ps;
      m = mnew;

#pragma unroll
      for (int r = 0; r < 4; ++r) {
        float cr = __shfl(corr, 4 * g + r);
#pragma unroll
        for (int cb = 0; cb < 4; ++cb) accv[cb][r] *= cr;
      }

      __builtin_amdgcn_s_setprio(1);
#pragma unroll
      for (int st = 0; st < 4; ++st) {
        bf16x4 pa;
#pragma unroll
        for (int jj = 0; jj < 4; ++jj) pa[jj] = (short)f2bf(p[st * 4 + jj]);
#pragma unroll
        for (int cb = 0; cb < 4; ++cb)
          accv[cb] = mfma16(pa, vb[st][cb], accv[cb]);
      }
      __builtin_amdgcn_s_setprio(0);
    }
  }

#pragma unroll
  for (int cb = 0; cb < 4; ++cb)
#pragma unroll
    for (int r = 0; r < 4; ++r) lacc[wid][cb * 4 + r][lane] = accv[cb][r];
  if (lane < 16) {
    lm[wid][lane] = m;
    ll[wid][lane] = lsum;
  }
  __syncthreads();

  float outv[4];
#pragma unroll
  for (int r = 0; r < 4; ++r) {
    const int row = 4 * g + r;
    float m0 = lm[0][row], m1 = lm[1][row], m2 = lm[2][row], m3 = lm[3][row];
    float mt = fmaxf(fmaxf(m0, m1), fmaxf(m2, m3));
    float e0 = __expf(m0 - mt), e1 = __expf(m1 - mt);
    float e2 = __expf(m2 - mt), e3 = __expf(m3 - mt);
    float ltot = ll[0][row] * e0 + ll[1][row] * e1 + ll[2][row] * e2 + ll[3][row] * e3;
    float a = lacc[0][wid * 4 + r][lane] * e0 + lacc[1][wid * 4 + r][lane] * e1 +
              lacc[2][wid * 4 + r][lane] * e2 + lacc[3][wid * 4 + r][lane] * e3;
    outv[r] = a / ltot;
  }
#pragma unroll
  for (int r = 0; r < 4; ++r)
    o[((size_t)(s0 + 4 * g + r) * NH + h) * HD + wid * 16 + l15] = outv[r];
}

// ---------------------------------------------------------------------------
// RMS-norm + sigmoid gate (vectorized x4); emits bf16.
// ---------------------------------------------------------------------------
__global__ __launch_bounds__(256) void postproc(const float* __restrict__ o,
                                                const float* __restrict__ g,
                                                const float* __restrict__ w,
                                                unsigned short* __restrict__ o2h) {
  int base = (blockIdx.x * 256 + threadIdx.x) * 4;
  int l16 = threadIdx.x & 15;
  float4 val = *reinterpret_cast<const float4*>(&o[base]);
  float ss = val.x * val.x + val.y * val.y + val.z * val.z + val.w * val.w;
#pragma unroll
  for (int off = 1; off < 16; off <<= 1) ss += __shfl_xor(ss, off);
  float r = rsqrtf(ss * (1.0f / HD) + 1e-6f);
  float4 gv = *reinterpret_cast<const float4*>(&g[base]);
  float f[4] = {val.x, val.y, val.z, val.w};
  float gg[4] = {gv.x, gv.y, gv.z, gv.w};
  unsigned short u[4];
#pragma unroll
  for (int j = 0; j < 4; ++j) {
    float sig = 1.0f / (1.0f + expf(-gg[j]));
    u[j] = f2bf(f[j] * r * w[l16 * 4 + j] * sig);
  }
  *reinterpret_cast<ushort4*>(&o2h[base]) = make_ushort4(u[0], u[1], u[2], u[3]);
}

// ---------------------------------------------------------------------------
extern "C" void kernel_launch(void* const* d_in, const int* in_sizes, int n_in,
                              void* d_out, int out_size, void* d_ws, size_t ws_size,
                              hipStream_t stream) {
  const float* x   = (const float*)d_in[0];
  const float* Wq  = (const float*)d_in[1];
  const float* Wk  = (const float*)d_in[2];
  const float* Wv  = (const float*)d_in[3];
  const float* Wo  = (const float*)d_in[4];
  const float* Wg1 = (const float*)d_in[5];
  const float* Wg2 = (const float*)d_in[6];
  const float* onw = (const float*)d_in[7];
  float* out = (float*)d_out;

  const size_t BIG = (size_t)S_LEN * D_DIM;  // 4M elements
  float* q    = (float*)d_ws;
  float* k    = q + BIG;
  float* v    = k + BIG;
  float* o    = v + BIG;
  float* gbuf = o + BIG;
  float* kg   = gbuf + BIG;                    // NCH*NH*HD
  int* amask  = (int*)(kg + NCH * NH * HD);    // NH*S
  float2* rtab = (float2*)(amask + NH * S_LEN);  // S*32 float2
  unsigned short* xh  = (unsigned short*)(rtab + S_LEN * 32);
  unsigned short* xl  = xh + BIG;
  unsigned short* whq = xl + BIG;
  unsigned short* wlq = whq + BIG;
  unsigned short* whk = wlq + BIG;
  unsigned short* wlk = whk + BIG;
  unsigned short* whv = wlk + BIG;
  unsigned short* whg = whv + BIG;
  unsigned short* who = whg + BIG;
  unsigned short* khf = who + BIG;
  unsigned short* vhf = khf + BIG;
  unsigned short* o2h = vhf + BIG;

  // RoPE cos/sin table (consumed by chunk_mean/gate_topk/repack_kvf/attn)
  rope_tab_k<<<(S_LEN * 32 + 255) / 256, 256, 0, stream>>>(rtab);
  // Split x into hi/lo bf16
  repack_x_hl<<<(int)(BIG / 4 / 256), 256, 0, stream>>>(x, xh, xl);
  // Fused weight repacks: Wq(lo), Wk(lo), Wv, Wo
  {
    RT4 rt;
    rt.W[0] = Wq; rt.hiT[0] = whq; rt.loT[0] = wlq; rt.has_lo[0] = 1;
    rt.W[1] = Wk; rt.hiT[1] = whk; rt.loT[1] = wlk; rt.has_lo[1] = 1;
    rt.W[2] = Wv; rt.hiT[2] = whv; rt.loT[2] = whv; rt.has_lo[2] = 0;
    rt.W[3] = Wo; rt.hiT[3] = who; rt.loT[3] = who; rt.has_lo[3] = 0;
    repack_T4<<<dim3(32, 32, 4), 256, 0, stream>>>(rt);
  }
  // W' = Wg1 @ Wg2 -> whg (bf16 transposed, direct)
  sgemm_f32T<<<dim3(16, 16), 256, 0, stream>>>(Wg1, Wg2, whg, D_DIM, D_DIM, HD);

  // Fused Q(3) K(3) V(1) G(1) projections (no rope here)
  {
    QKVG gg;
    gg.xh = xh; gg.xl = xl;
    gg.wh[0] = whq; gg.wh[1] = whk; gg.wh[2] = whv; gg.wh[3] = whg;
    gg.wl[0] = wlq; gg.wl[1] = wlk; gg.wl[2] = nullptr; gg.wl[3] = nullptr;
    gg.C[0] = q; gg.C[1] = k; gg.C[2] = v; gg.C[3] = gbuf;
    gg.np[0] = 3; gg.np[1] = 3; gg.np[2] = 1; gg.np[3] = 1;
    gemm_qkvg<<<1024, 256, 0, stream>>>(gg);
  }

  // Chunk means of rope(k) + gating on rope(q) (fp32)
  chunk_mean<<<(NCH * NH * HD + 255) / 256, 256, 0, stream>>>(k, rtab, kg);
  gate_topk<<<dim3(S_LEN / 4, NH), 256, 0, stream>>>(q, rtab, kg, amask);
  // Fragment-major K/V repack with fused K-rope
  repack_kvf<<<dim3(S_LEN / 64, NH), 256, 0, stream>>>(k, v, rtab, khf, vhf);
  // Attention (q-rope fused in qf build; overwrites o)
  attn_mfma<<<(S_LEN / 16) * NH, 256, 0, stream>>>(q, rtab, khf, vhf, amask, o);
  // RMS-norm + sigmoid gate -> bf16
  postproc<<<(int)(BIG / 4 / 256), 256, 0, stream>>>(o, gbuf, onw, o2h);
  // out = o2 @ Wo
  {
    G3 g3{{o2h, o2h, o2h}, {who, who, who}, 1};
    gemm_bt<<<(S_LEN / 64) * (D_DIM / 128), 256, 0, stream>>>(g3, out, S_LEN, D_DIM, D_DIM);
  }
}

// Round 18
// 341.411 us; speedup vs baseline: 1.0655x; 1.0655x over previous
//
#include <hip/hip_runtime.h>
#include <hip/hip_bf16.h>
#include <math.h>

#define S_LEN 2048
#define D_DIM 2048
#define NH 32
#define HD 64
#define CS 256
#define NCH 8

typedef __attribute__((ext_vector_type(8))) short bf16x8;
typedef __attribute__((ext_vector_type(4))) short bf16x4;
typedef __attribute__((ext_vector_type(4))) float f32x4;

__device__ __forceinline__ unsigned short f2bf(float f) {
  unsigned int u = __builtin_bit_cast(unsigned int, f);
  unsigned int r = (u + 0x7fffu + ((u >> 16) & 1u)) >> 16;
  return (unsigned short)r;
}
__device__ __forceinline__ float bf2f(unsigned short b) {
  unsigned int u = ((unsigned int)b) << 16;
  return __builtin_bit_cast(float, u);
}

__device__ __forceinline__ f32x4 mfma16(bf16x4 a, bf16x4 b, f32x4 c) {
#if __has_builtin(__builtin_amdgcn_mfma_f32_16x16x16_bf16)
  return __builtin_amdgcn_mfma_f32_16x16x16_bf16(a, b, c, 0, 0, 0);
#elif __has_builtin(__builtin_amdgcn_mfma_f32_16x16x16bf16_1k)
  return __builtin_amdgcn_mfma_f32_16x16x16bf16_1k(a, b, c, 0, 0, 0);
#else
  asm("v_mfma_f32_16x16x16_bf16 %0, %1, %2, %0" : "+v"(c) : "v"(a), "v"(b));
  return c;
#endif
}

__device__ __forceinline__ void gload16(const void* gp, void* lp) {
  __builtin_amdgcn_global_load_lds(
      (const __attribute__((address_space(1))) unsigned int*)gp,
      (__attribute__((address_space(3))) unsigned int*)lp, 16, 0, 0);
}

// ---------------------------------------------------------------------------
// RoPE cos/sin table: rope_tab[s][d] = (cosf(s*inv(d)), sinf(s*inv(d))).
// ---------------------------------------------------------------------------
__global__ __launch_bounds__(256) void rope_tab_k(float2* __restrict__ tab) {
  int idx = blockIdx.x * 256 + threadIdx.x;
  if (idx >= S_LEN * 32) return;
  int d = idx & 31;
  int s = idx >> 5;
  float inv = 1.0f / powf(10000.0f, (float)d * (1.0f / 32.0f));
  float fr = (float)s * inv;
  tab[idx] = make_float2(cosf(fr), sinf(fr));
}

// ---------------------------------------------------------------------------
// Fused QKVG GEMM, 128x128 tile, BK=64, 32KB LDS, RoPE epilogue on Q,K.
// Epilogue: fully-unrolled per-m blocks (static indices only) with
// sched_barrier(0) at block boundaries so the rtab loads are NOT hoisted
// (R13: hoist -> VGPR 112 -> 4 blocks/CU; target <=102 -> 5 blocks/CU).
// ---------------------------------------------------------------------------
struct QKVG {
  const unsigned short* xh;
  const unsigned short* xl;
  const unsigned short* wh[4];
  const unsigned short* wl[4];
  float* C[4];
  int np[4];
  const float2* rtab;
};

__global__ __launch_bounds__(256) void gemm_qkvg(QKVG g) {
  __shared__ __align__(16) unsigned short Als[128 * 64];
  __shared__ __align__(16) unsigned short Bls[128 * 64];
  const int tid = threadIdx.x;
  const int wid = tid >> 6, lane = tid & 63;
  const int l15 = lane & 15, l4 = lane >> 4;
  const int wr = wid >> 1, wc = wid & 1;
  const int K = D_DIM, N = D_DIM;

  const int bid = blockIdx.x;
  const int xcd = bid & 7;
  const int local = bid >> 3;
  const int c = local >> 6;
  const int idx = local & 63;
  const int out = (xcd & 1) + 2 * c;
  const int grp = xcd >> 1;
  const int row0 = (idx >> 2) << 7;
  const int col0 = ((grp << 2) + (idx & 3)) << 7;

  f32x4 acc[4][4];
#pragma unroll
  for (int m = 0; m < 4; ++m)
#pragma unroll
    for (int n = 0; n < 4; ++n) acc[m][n] = (f32x4){0.f, 0.f, 0.f, 0.f};

  const int np = g.np[out];
  for (int p = 0; p < np; ++p) {
    const unsigned short* Ap = (p == 2) ? g.xl : g.xh;
    const unsigned short* Bp = (p == 1) ? g.wl[out] : g.wh[out];
    for (int kt = 0; kt < K; kt += 64) {
      __syncthreads();
#pragma unroll
      for (int i = 0; i < 4; ++i) {
        const int Lb = i * 4096 + wid * 1024;
        const int L = Lb + lane * 16;
        const int row = L >> 7;
        const int s = (L >> 4) & 7;
        const int cofs = (s ^ (row & 7)) << 3;
        gload16(Ap + (size_t)(row0 + row) * K + kt + cofs, (char*)Als + Lb);
        gload16(Bp + (size_t)(col0 + row) * K + kt + cofs, (char*)Bls + Lb);
      }
      asm volatile("s_waitcnt vmcnt(0)" ::: "memory");
      __syncthreads();
#pragma unroll
      for (int ks = 0; ks < 2; ++ks) {
        bf16x8 af[4], bfr[4];
#pragma unroll
        for (int m = 0; m < 4; ++m) {
          int row = wr * 64 + m * 16 + l15;
          int s = (ks * 4 + l4) ^ (row & 7);
          af[m] = *reinterpret_cast<const bf16x8*>(&Als[row * 64 + s * 8]);
        }
#pragma unroll
        for (int n = 0; n < 4; ++n) {
          int col = wc * 64 + n * 16 + l15;
          int s = (ks * 4 + l4) ^ (col & 7);
          bfr[n] = *reinterpret_cast<const bf16x8*>(&Bls[col * 64 + s * 8]);
        }
#pragma unroll
        for (int m = 0; m < 4; ++m)
#pragma unroll
          for (int n = 0; n < 4; ++n)
            acc[m][n] = __builtin_amdgcn_mfma_f32_16x16x32_bf16(af[m], bfr[n], acc[m][n], 0, 0, 0);
      }
    }
  }

  // Fused RoPE for Q,K: pair (n, n+2) = head-dims (d, d+32), d = n*16+l15.
  // Static indices only; sched_barrier(0) bounds cs register lifetime per m.
  if (out < 2) {
#pragma unroll
    for (int m = 0; m < 4; ++m) {
      __builtin_amdgcn_sched_barrier(0);
      float2 cs0[4], cs1[4];
#pragma unroll
      for (int r = 0; r < 4; ++r) {
        const int s = row0 + wr * 64 + m * 16 + l4 * 4 + r;
        cs0[r] = g.rtab[s * 32 + l15];
        cs1[r] = g.rtab[s * 32 + 16 + l15];
      }
#pragma unroll
      for (int r = 0; r < 4; ++r) {
        float a1 = acc[m][0][r], a2 = acc[m][2][r];
        acc[m][0][r] = a1 * cs0[r].x - a2 * cs0[r].y;
        acc[m][2][r] = a2 * cs0[r].x + a1 * cs0[r].y;
        float b1 = acc[m][1][r], b2 = acc[m][3][r];
        acc[m][1][r] = b1 * cs1[r].x - b2 * cs1[r].y;
        acc[m][3][r] = b2 * cs1[r].x + b1 * cs1[r].y;
      }
    }
    __builtin_amdgcn_sched_barrier(0);
  }

  float* C = g.C[out];
#pragma unroll
  for (int m = 0; m < 4; ++m)
#pragma unroll
    for (int n = 0; n < 4; ++n)
#pragma unroll
      for (int r = 0; r < 4; ++r)
        C[(size_t)(row0 + wr * 64 + m * 16 + l4 * 4 + r) * N + col0 + wc * 64 + n * 16 + l15] =
            acc[m][n][r];
}

// ---------------------------------------------------------------------------
// bf16 MFMA GEMM 64x128 (out-projection).
// ---------------------------------------------------------------------------
struct G3 {
  const unsigned short* A[3];
  const unsigned short* B[3];
  int np;
};

__global__ __launch_bounds__(256) void gemm_bt(G3 g, float* __restrict__ C,
                                               int M, int N, int K) {
  __shared__ __align__(16) unsigned short Als[64 * 64];
  __shared__ __align__(16) unsigned short Bls[128 * 64];
  const int tid = threadIdx.x;
  const int wid = tid >> 6, lane = tid & 63;
  const int l15 = lane & 15, l4 = lane >> 4;
  const int wr = wid >> 1, wc = wid & 1;
  const int nbx = N >> 7;
  int bid = blockIdx.x;
  const int nwg = gridDim.x;
  if ((nwg & 7) == 0) {
    int q = nwg >> 3;
    bid = (bid & 7) * q + (bid >> 3);
  }
  const int row0 = (bid / nbx) << 6;
  const int col0 = (bid % nbx) << 7;

  f32x4 acc[2][4];
#pragma unroll
  for (int m = 0; m < 2; ++m)
#pragma unroll
    for (int n = 0; n < 4; ++n) acc[m][n] = (f32x4){0.f, 0.f, 0.f, 0.f};

  for (int p = 0; p < g.np; ++p) {
    const unsigned short* Ap = g.A[p];
    const unsigned short* Bp = g.B[p];
    for (int kt = 0; kt < K; kt += 64) {
      __syncthreads();
#pragma unroll
      for (int i = 0; i < 2; ++i) {
        const int Lb = i * 4096 + wid * 1024;
        const int L = Lb + lane * 16;
        const int row = L >> 7;
        const int s = (L >> 4) & 7;
        const int cofs = (s ^ (row & 7)) << 3;
        gload16(Ap + (size_t)(row0 + row) * K + kt + cofs, (char*)Als + Lb);
      }
#pragma unroll
      for (int i = 0; i < 4; ++i) {
        const int Lb = i * 4096 + wid * 1024;
        const int L = Lb + lane * 16;
        const int row = L >> 7;
        const int s = (L >> 4) & 7;
        const int cofs = (s ^ (row & 7)) << 3;
        gload16(Bp + (size_t)(col0 + row) * K + kt + cofs, (char*)Bls + Lb);
      }
      asm volatile("s_waitcnt vmcnt(0)" ::: "memory");
      __syncthreads();
#pragma unroll
      for (int ks = 0; ks < 2; ++ks) {
        bf16x8 af[2], bfr[4];
#pragma unroll
        for (int m = 0; m < 2; ++m) {
          int row = wr * 32 + m * 16 + l15;
          int s = (ks * 4 + l4) ^ (row & 7);
          af[m] = *reinterpret_cast<const bf16x8*>(&Als[row * 64 + s * 8]);
        }
#pragma unroll
        for (int n = 0; n < 4; ++n) {
          int col = wc * 64 + n * 16 + l15;
          int s = (ks * 4 + l4) ^ (col & 7);
          bfr[n] = *reinterpret_cast<const bf16x8*>(&Bls[col * 64 + s * 8]);
        }
#pragma unroll
        for (int m = 0; m < 2; ++m)
#pragma unroll
          for (int n = 0; n < 4; ++n)
            acc[m][n] = __builtin_amdgcn_mfma_f32_16x16x32_bf16(af[m], bfr[n], acc[m][n], 0, 0, 0);
      }
    }
  }

#pragma unroll
  for (int m = 0; m < 2; ++m)
#pragma unroll
    for (int n = 0; n < 4; ++n)
#pragma unroll
      for (int r = 0; r < 4; ++r)
        C[(size_t)(row0 + wr * 32 + m * 16 + l4 * 4 + r) * N + col0 + wc * 64 + n * 16 + l15] =
            acc[m][n][r];
}

// ---------------------------------------------------------------------------
// fp32 SGEMM for W' = Wg1 @ Wg2 (K=64), writing W'^T bf16 directly.
// ---------------------------------------------------------------------------
__global__ __launch_bounds__(256) void sgemm_f32T(const float* __restrict__ A,
                                                  const float* __restrict__ B,
                                                  unsigned short* __restrict__ CT,
                                                  int M, int N, int K) {
  __shared__ float As[8][128];
  __shared__ float Bs[8][128];
  const int tid = threadIdx.x;
  const int row0 = blockIdx.y * 128;
  const int col0 = blockIdx.x * 128;
  const int tm = (tid / 16) * 8;
  const int tn = (tid % 16) * 8;
  const int arow = tid >> 1;
  const int acol = (tid & 1) * 4;
  const int brow = tid >> 5;
  const int bcol = (tid & 31) * 4;

  float acc[8][8];
#pragma unroll
  for (int i = 0; i < 8; ++i)
#pragma unroll
    for (int j = 0; j < 8; ++j) acc[i][j] = 0.f;

  for (int k0 = 0; k0 < K; k0 += 8) {
    float4 av = make_float4(0.f, 0.f, 0.f, 0.f);
    if (row0 + arow < M) {
      int kb = k0 + acol;
      av = *reinterpret_cast<const float4*>(&A[(size_t)(row0 + arow) * K + kb]);
    }
    As[acol + 0][arow] = av.x;
    As[acol + 1][arow] = av.y;
    As[acol + 2][arow] = av.z;
    As[acol + 3][arow] = av.w;
    float4 bv = make_float4(0.f, 0.f, 0.f, 0.f);
    if (k0 + brow < K) {
      bv = *reinterpret_cast<const float4*>(&B[(size_t)(k0 + brow) * N + col0 + bcol]);
    }
    *reinterpret_cast<float4*>(&Bs[brow][bcol]) = bv;
    __syncthreads();
#pragma unroll
    for (int kk = 0; kk < 8; ++kk) {
      float a[8], b[8];
      *reinterpret_cast<float4*>(&a[0]) = *reinterpret_cast<const float4*>(&As[kk][tm]);
      *reinterpret_cast<float4*>(&a[4]) = *reinterpret_cast<const float4*>(&As[kk][tm + 4]);
      *reinterpret_cast<float4*>(&b[0]) = *reinterpret_cast<const float4*>(&Bs[kk][tn]);
      *reinterpret_cast<float4*>(&b[4]) = *reinterpret_cast<const float4*>(&Bs[kk][tn + 4]);
#pragma unroll
      for (int i = 0; i < 8; ++i)
#pragma unroll
        for (int j = 0; j < 8; ++j) acc[i][j] = fmaf(a[i], b[j], acc[i][j]);
    }
    __syncthreads();
  }
#pragma unroll
  for (int j = 0; j < 8; ++j) {
    const int n = col0 + tn + j;
    ushort4 u0 = make_ushort4(f2bf(acc[0][j]), f2bf(acc[1][j]), f2bf(acc[2][j]), f2bf(acc[3][j]));
    ushort4 u1 = make_ushort4(f2bf(acc[4][j]), f2bf(acc[5][j]), f2bf(acc[6][j]), f2bf(acc[7][j]));
    *reinterpret_cast<ushort4*>(&CT[(size_t)n * M + row0 + tm]) = u0;
    *reinterpret_cast<ushort4*>(&CT[(size_t)n * M + row0 + tm + 4]) = u1;
  }
}

// ---------------------------------------------------------------------------
// x fp32 -> xh, xl bf16 (hi/lo split).
// ---------------------------------------------------------------------------
__global__ __launch_bounds__(256) void repack_x_hl(const float* __restrict__ x,
                                                   unsigned short* __restrict__ xh,
                                                   unsigned short* __restrict__ xl) {
  int i = (blockIdx.x * 256 + threadIdx.x) * 4;
  float4 v = *reinterpret_cast<const float4*>(&x[i]);
  float f[4] = {v.x, v.y, v.z, v.w};
  unsigned short h[4], l[4];
#pragma unroll
  for (int j = 0; j < 4; ++j) {
    h[j] = f2bf(f[j]);
    l[j] = f2bf(f[j] - bf2f(h[j]));
  }
  *reinterpret_cast<ushort4*>(&xh[i]) = make_ushort4(h[0], h[1], h[2], h[3]);
  *reinterpret_cast<ushort4*>(&xl[i]) = make_ushort4(l[0], l[1], l[2], l[3]);
}

// ---------------------------------------------------------------------------
// Fused 4-weight transpose repack (Wq, Wk with lo; Wv, Wo hi-only).
// ---------------------------------------------------------------------------
struct RT4 {
  const float* W[4];
  unsigned short* hiT[4];
  unsigned short* loT[4];
  int has_lo[4];
};

__global__ __launch_bounds__(256) void repack_T4(RT4 a) {
  __shared__ float t[64][65];
  const int wsel = blockIdx.z;
  const float* W = a.W[wsel];
  unsigned short* hiT = a.hiT[wsel];
  unsigned short* loT = a.loT[wsel];
  const int has_lo = a.has_lo[wsel];
  const int k0 = blockIdx.y * 64, n0 = blockIdx.x * 64;
  const int tid = threadIdx.x;
  const int c = tid & 63, rr = tid >> 6;
#pragma unroll
  for (int r = 0; r < 16; ++r) {
    int kr = r * 4 + rr;
    t[kr][c] = W[(size_t)(k0 + kr) * D_DIM + n0 + c];
  }
  __syncthreads();
#pragma unroll
  for (int r = 0; r < 16; ++r) {
    int n = r * 4 + rr;
    float f = t[c][n];
    unsigned short hb = f2bf(f);
    hiT[(size_t)(n0 + n) * D_DIM + k0 + c] = hb;
    if (has_lo) loT[(size_t)(n0 + n) * D_DIM + k0 + c] = f2bf(f - bf2f(hb));
  }
}

// ---------------------------------------------------------------------------
// Chunk means of k (k already roped by gemm_qkvg epilogue).
// ---------------------------------------------------------------------------
__global__ __launch_bounds__(256) void chunk_mean(const float* __restrict__ k,
                                                  float* __restrict__ kg) {
  int idx = blockIdx.x * 256 + threadIdx.x;
  if (idx >= NCH * NH * HD) return;
  int c = idx / (NH * HD);
  int hd = idx % (NH * HD);
  float sum = 0.f;
  for (int t = 0; t < CS; ++t) sum += k[(size_t)(c * CS + t) * (NH * HD) + hd];
  kg[idx] = sum * (1.0f / CS);
}

// ---------------------------------------------------------------------------
// Gate + top-3-past chunk selection (fp32; q already roped).
// ---------------------------------------------------------------------------
__global__ __launch_bounds__(256) void gate_topk(const float* __restrict__ q,
                                                 const float* __restrict__ kg,
                                                 int* __restrict__ amask) {
  int wid = threadIdx.x >> 6;
  int lane = threadIdx.x & 63;
  int s = blockIdx.x * 4 + wid;
  int h = blockIdx.y;
  int myc = s >> 8;
  float qd = q[((size_t)s * NH + h) * HD + lane];
  float g[NCH];
#pragma unroll
  for (int c = 0; c < NCH; ++c) {
    float p = qd * kg[((size_t)c * NH + h) * HD + lane];
#pragma unroll
    for (int off = 32; off; off >>= 1) p += __shfl_xor(p, off);
    g[c] = p;
  }
  int chosen = 0;
#pragma unroll
  for (int pick = 0; pick < 3; ++pick) {
    float best = -INFINITY;
    int bi = -1;
#pragma unroll
    for (int c = 0; c < NCH; ++c) {
      if (c < myc && !((chosen >> c) & 1) && g[c] > best) {
        best = g[c];
        bi = c;
      }
    }
    if (bi >= 0) chosen |= (1 << bi);
  }
  int mask = chosen | (1 << myc);
  if (lane == 0) amask[h * S_LEN + s] = mask;
}

// ---------------------------------------------------------------------------
// K,V fp32 [s][h][d] -> fragment-major bf16 (one kernel, both outputs).
// ---------------------------------------------------------------------------
__global__ __launch_bounds__(256) void repack_kvf(const float* __restrict__ k,
                                                  const float* __restrict__ v,
                                                  unsigned short* __restrict__ khf,
                                                  unsigned short* __restrict__ vhf) {
  __shared__ float tk[64][68];
  __shared__ float tv[64][68];
  const int t = blockIdx.x;
  const int h = blockIdx.y;
  const int tid = threadIdx.x;
  const int t0 = t * 64;
  {
    const int r = tid >> 2, c4 = (tid & 3) * 16;
    const float* sk = &k[((size_t)(t0 + r) * NH + h) * HD + c4];
    const float* sv = &v[((size_t)(t0 + r) * NH + h) * HD + c4];
#pragma unroll
    for (int qd = 0; qd < 4; ++qd) {
      *reinterpret_cast<float4*>(&tk[r][c4 + qd * 4]) =
          *reinterpret_cast<const float4*>(sk + qd * 4);
      *reinterpret_cast<float4*>(&tv[r][c4 + qd * 4]) =
          *reinterpret_cast<const float4*>(sv + qd * 4);
    }
  }
  __syncthreads();
  const int w = tid >> 6, l = tid & 63;
  const int l15 = l & 15, g = l >> 4;
  unsigned short* obk = khf + (((size_t)h * 32 + t) * 8) * 512;
  unsigned short* obv = vhf + (((size_t)h * 32 + t) * 8) * 512;
#pragma unroll
  for (int ff = 0; ff < 2; ++ff) {
    const int f = 2 * w + ff;
    {
      const int st = f >> 1, half = f & 1;
      const float* rp = &tk[st * 16 + l15][g * 8 + half * 32];
      ushort4 u0 = make_ushort4(f2bf(rp[0]), f2bf(rp[1]), f2bf(rp[2]), f2bf(rp[3]));
      ushort4 u1 = make_ushort4(f2bf(rp[4]), f2bf(rp[5]), f2bf(rp[6]), f2bf(rp[7]));
      *reinterpret_cast<ushort4*>(obk + (size_t)f * 512 + l * 8) = u0;
      *reinterpret_cast<ushort4*>(obk + (size_t)f * 512 + l * 8 + 4) = u1;
    }
    {
      const int st = f >> 1, p = f & 1;
      unsigned short u[8];
#pragma unroll
      for (int e = 0; e < 8; ++e) {
        const int cb = 2 * p + (e >> 2);
        const int j = e & 3;
        u[e] = f2bf(tv[st * 16 + 4 * g + j][cb * 16 + l15]);
      }
      *reinterpret_cast<ushort4*>(obv + (size_t)f * 512 + l * 8) =
          make_ushort4(u[0], u[1], u[2], u[3]);
      *reinterpret_cast<ushort4*>(obv + (size_t)f * 512 + l * 8 + 4) =
          make_ushort4(u[4], u[5], u[6], u[7]);
    }
  }
}

// ---------------------------------------------------------------------------
// MFMA flash attention, split-K across 4 waves, fragment-major K/V loads.
// ---------------------------------------------------------------------------
__global__ __launch_bounds__(256) void attn_mfma(const float* __restrict__ q,
                                                 const unsigned short* __restrict__ khf,
                                                 const unsigned short* __restrict__ vhf,
                                                 const int* __restrict__ amask,
                                                 float* __restrict__ o) {
  const int B = blockIdx.x;
  const int xcd = B & 7;
  const int jb = B >> 3;
  const int h = xcd + ((jb >> 7) << 3);
  const int s0 = (jb & 127) << 4;
  const int tid = threadIdx.x;
  const int wid = tid >> 6;
  const int lane = tid & 63;
  const int l15 = lane & 15, g = lane >> 4;
  const int myS = s0 + l15;
  const int myc = s0 >> 8;
  const int ktm = (s0 & (CS - 1)) >> 6;

  __shared__ float lm[4][16];
  __shared__ float ll[4][16];
  __shared__ float lacc[4][16][64];

  const float* qrow = q + ((size_t)myS * NH + h) * HD;
  bf16x8 qf[2];
#pragma unroll
  for (int hf = 0; hf < 2; ++hf)
#pragma unroll
    for (int jj = 0; jj < 8; ++jj)
      qf[hf][jj] = (short)f2bf(qrow[hf * 32 + g * 8 + jj] * 0.125f);

  int mymask = amask[h * S_LEN + myS];
  int wmask = mymask;
  wmask |= __shfl_xor(wmask, 1);
  wmask |= __shfl_xor(wmask, 2);
  wmask |= __shfl_xor(wmask, 4);
  wmask |= __shfl_xor(wmask, 8);
  const int pmask = wmask & ~(1 << myc);
  const int ntot = (ktm + 1) + 4 * __popc(pmask);

  auto DEC = [&](int j) -> int {
    if (j <= ktm) return ((s0 & ~255) + (j << 6)) | (1 << 16);
    int jj = j - ktm - 1;
    int mm = pmask;
    int drop = jj >> 2;
    for (int b = 0; b < drop; ++b) mm &= mm - 1;
    int c = __ffs(mm) - 1;
    return ((c << 8) + ((jj & 3) << 6)) | (((mymask >> c) & 1) << 16);
  };

  const unsigned short* khh = khf + (((size_t)h * 32) << 12);
  const unsigned short* vhh = vhf + (((size_t)h * 32) << 12);

  bf16x8 kr[4][2];
  auto LOADK = [&](int t0) {
    const unsigned short* tb = khh + ((size_t)(t0 >> 6) << 12) + lane * 8;
#pragma unroll
    for (int f = 0; f < 8; ++f)
      kr[f >> 1][f & 1] = *reinterpret_cast<const bf16x8*>(tb + f * 512);
  };

  float m = -1e30f, lsum = 0.f;
  f32x4 accv[4];
#pragma unroll
  for (int i = 0; i < 4; ++i) accv[i] = (f32x4){0.f, 0.f, 0.f, 0.f};

  if (wid < ntot) LOADK(DEC(wid) & 0xFFFF);

#pragma unroll
  for (int i = 0; i < 8; ++i) {
    const int j = wid + (i << 2);
    if (j < ntot) {
      const int ent = DEC(j);
      const int t0 = ent & 0xFFFF;
      const bool lane_on = (ent >> 16) != 0;
      const bool diag = (j == ktm);

      const unsigned short* vtb = vhh + ((size_t)(t0 >> 6) << 12) + lane * 8;
      bf16x4 vb[4][4];
#pragma unroll
      for (int fp = 0; fp < 8; ++fp) {
        bf16x8 wv = *reinterpret_cast<const bf16x8*>(vtb + fp * 512);
        const int st = fp >> 1, pp = fp & 1;
#pragma unroll
        for (int jj = 0; jj < 4; ++jj) {
          vb[st][2 * pp][jj] = wv[jj];
          vb[st][2 * pp + 1][jj] = wv[4 + jj];
        }
      }

      float p[16];
      __builtin_amdgcn_s_setprio(1);
#pragma unroll
      for (int st = 0; st < 4; ++st) {
        f32x4 d = (f32x4){0.f, 0.f, 0.f, 0.f};
        d = __builtin_amdgcn_mfma_f32_16x16x32_bf16(kr[st][0], qf[0], d, 0, 0, 0);
        d = __builtin_amdgcn_mfma_f32_16x16x32_bf16(kr[st][1], qf[1], d, 0, 0, 0);
#pragma unroll
        for (int r = 0; r < 4; ++r) {
          bool ok = lane_on && (!diag || (t0 + st * 16 + 4 * g + r <= myS));
          p[st * 4 + r] = ok ? d[r] : -1e30f;
        }
      }
      __builtin_amdgcn_s_setprio(0);

      if (j + 4 < ntot) LOADK(DEC(j + 4) & 0xFFFF);

      float mt = -1e30f;
#pragma unroll
      for (int ii = 0; ii < 16; ++ii) mt = fmaxf(mt, p[ii]);
      mt = fmaxf(mt, __shfl_xor(mt, 16));
      mt = fmaxf(mt, __shfl_xor(mt, 32));

      const float mnew = fmaxf(m, mt);
      const float corr = __expf(m - mnew);
      float ps = 0.f;
#pragma unroll
      for (int ii = 0; ii < 16; ++ii) {
        float pv = (p[ii] > -1e29f) ? __expf(p[ii] - mnew) : 0.f;
        p[ii] = pv;
        ps += pv;
      }
      ps += __shfl_xor(ps, 16);
      ps += __shfl_xor(ps, 32);
      lsum = lsum * corr + ps;
      m = mnew;

#pragma unroll
      for (int r = 0; r < 4; ++r) {
        float cr = __shfl(corr, 4 * g + r);
#pragma unroll
        for (int cb = 0; cb < 4; ++cb) accv[cb][r] *= cr;
      }

      __builtin_amdgcn_s_setprio(1);
#pragma unroll
      for (int st = 0; st < 4; ++st) {
        bf16x4 pa;
#pragma unroll
        for (int jj = 0; jj < 4; ++jj) pa[jj] = (short)f2bf(p[st * 4 + jj]);
#pragma unroll
        for (int cb = 0; cb < 4; ++cb)
          accv[cb] = mfma16(pa, vb[st][cb], accv[cb]);
      }
      __builtin_amdgcn_s_setprio(0);
    }
  }

#pragma unroll
  for (int cb = 0; cb < 4; ++cb)
#pragma unroll
    for (int r = 0; r < 4; ++r) lacc[wid][cb * 4 + r][lane] = accv[cb][r];
  if (lane < 16) {
    lm[wid][lane] = m;
    ll[wid][lane] = lsum;
  }
  __syncthreads();

  float outv[4];
#pragma unroll
  for (int r = 0; r < 4; ++r) {
    const int row = 4 * g + r;
    float m0 = lm[0][row], m1 = lm[1][row], m2 = lm[2][row], m3 = lm[3][row];
    float mt = fmaxf(fmaxf(m0, m1), fmaxf(m2, m3));
    float e0 = __expf(m0 - mt), e1 = __expf(m1 - mt);
    float e2 = __expf(m2 - mt), e3 = __expf(m3 - mt);
    float ltot = ll[0][row] * e0 + ll[1][row] * e1 + ll[2][row] * e2 + ll[3][row] * e3;
    float a = lacc[0][wid * 4 + r][lane] * e0 + lacc[1][wid * 4 + r][lane] * e1 +
              lacc[2][wid * 4 + r][lane] * e2 + lacc[3][wid * 4 + r][lane] * e3;
    outv[r] = a / ltot;
  }
#pragma unroll
  for (int r = 0; r < 4; ++r)
    o[((size_t)(s0 + 4 * g + r) * NH + h) * HD + wid * 16 + l15] = outv[r];
}

// ---------------------------------------------------------------------------
// RMS-norm + sigmoid gate (vectorized x4); emits bf16.
// ---------------------------------------------------------------------------
__global__ __launch_bounds__(256) void postproc(const float* __restrict__ o,
                                                const float* __restrict__ g,
                                                const float* __restrict__ w,
                                                unsigned short* __restrict__ o2h) {
  int base = (blockIdx.x * 256 + threadIdx.x) * 4;
  int l16 = threadIdx.x & 15;
  float4 val = *reinterpret_cast<const float4*>(&o[base]);
  float ss = val.x * val.x + val.y * val.y + val.z * val.z + val.w * val.w;
#pragma unroll
  for (int off = 1; off < 16; off <<= 1) ss += __shfl_xor(ss, off);
  float r = rsqrtf(ss * (1.0f / HD) + 1e-6f);
  float4 gv = *reinterpret_cast<const float4*>(&g[base]);
  float f[4] = {val.x, val.y, val.z, val.w};
  float gg[4] = {gv.x, gv.y, gv.z, gv.w};
  unsigned short u[4];
#pragma unroll
  for (int j = 0; j < 4; ++j) {
    float sig = 1.0f / (1.0f + expf(-gg[j]));
    u[j] = f2bf(f[j] * r * w[l16 * 4 + j] * sig);
  }
  *reinterpret_cast<ushort4*>(&o2h[base]) = make_ushort4(u[0], u[1], u[2], u[3]);
}

// ---------------------------------------------------------------------------
extern "C" void kernel_launch(void* const* d_in, const int* in_sizes, int n_in,
                              void* d_out, int out_size, void* d_ws, size_t ws_size,
                              hipStream_t stream) {
  const float* x   = (const float*)d_in[0];
  const float* Wq  = (const float*)d_in[1];
  const float* Wk  = (const float*)d_in[2];
  const float* Wv  = (const float*)d_in[3];
  const float* Wo  = (const float*)d_in[4];
  const float* Wg1 = (const float*)d_in[5];
  const float* Wg2 = (const float*)d_in[6];
  const float* onw = (const float*)d_in[7];
  float* out = (float*)d_out;

  const size_t BIG = (size_t)S_LEN * D_DIM;  // 4M elements
  float* q    = (float*)d_ws;
  float* k    = q + BIG;
  float* v    = k + BIG;
  float* o    = v + BIG;
  float* gbuf = o + BIG;
  float* kg   = gbuf + BIG;                    // NCH*NH*HD
  int* amask  = (int*)(kg + NCH * NH * HD);    // NH*S
  float2* rtab = (float2*)(amask + NH * S_LEN);  // S*32 float2
  unsigned short* xh  = (unsigned short*)(rtab + S_LEN * 32);
  unsigned short* xl  = xh + BIG;
  unsigned short* whq = xl + BIG;
  unsigned short* wlq = whq + BIG;
  unsigned short* whk = wlq + BIG;
  unsigned short* wlk = whk + BIG;
  unsigned short* whv = wlk + BIG;
  unsigned short* whg = whv + BIG;
  unsigned short* who = whg + BIG;
  unsigned short* khf = who + BIG;
  unsigned short* vhf = khf + BIG;
  unsigned short* o2h = vhf + BIG;

  // RoPE cos/sin table (consumed by gemm_qkvg epilogue)
  rope_tab_k<<<(S_LEN * 32 + 255) / 256, 256, 0, stream>>>(rtab);
  // Split x into hi/lo bf16
  repack_x_hl<<<(int)(BIG / 4 / 256), 256, 0, stream>>>(x, xh, xl);
  // Fused weight repacks: Wq(lo), Wk(lo), Wv, Wo
  {
    RT4 rt;
    rt.W[0] = Wq; rt.hiT[0] = whq; rt.loT[0] = wlq; rt.has_lo[0] = 1;
    rt.W[1] = Wk; rt.hiT[1] = whk; rt.loT[1] = wlk; rt.has_lo[1] = 1;
    rt.W[2] = Wv; rt.hiT[2] = whv; rt.loT[2] = whv; rt.has_lo[2] = 0;
    rt.W[3] = Wo; rt.hiT[3] = who; rt.loT[3] = who; rt.has_lo[3] = 0;
    repack_T4<<<dim3(32, 32, 4), 256, 0, stream>>>(rt);
  }
  // W' = Wg1 @ Wg2 -> whg (bf16 transposed, direct)
  sgemm_f32T<<<dim3(16, 16), 256, 0, stream>>>(Wg1, Wg2, whg, D_DIM, D_DIM, HD);

  // Fused Q(3) K(3) V(1) G(1) projections + RoPE epilogue on Q,K
  {
    QKVG gg;
    gg.xh = xh; gg.xl = xl;
    gg.wh[0] = whq; gg.wh[1] = whk; gg.wh[2] = whv; gg.wh[3] = whg;
    gg.wl[0] = wlq; gg.wl[1] = wlk; gg.wl[2] = nullptr; gg.wl[3] = nullptr;
    gg.C[0] = q; gg.C[1] = k; gg.C[2] = v; gg.C[3] = gbuf;
    gg.np[0] = 3; gg.np[1] = 3; gg.np[2] = 1; gg.np[3] = 1;
    gg.rtab = rtab;
    gemm_qkvg<<<1024, 256, 0, stream>>>(gg);
  }

  // Chunk means + gating (fp32; q,k already roped)
  chunk_mean<<<(NCH * NH * HD + 255) / 256, 256, 0, stream>>>(k, kg);
  gate_topk<<<dim3(S_LEN / 4, NH), 256, 0, stream>>>(q, kg, amask);
  // Fragment-major K/V repack (fused)
  repack_kvf<<<dim3(S_LEN / 64, NH), 256, 0, stream>>>(k, v, khf, vhf);
  // Attention (overwrites o)
  attn_mfma<<<(S_LEN / 16) * NH, 256, 0, stream>>>(q, khf, vhf, amask, o);
  // RMS-norm + sigmoid gate -> bf16
  postproc<<<(int)(BIG / 4 / 256), 256, 0, stream>>>(o, gbuf, onw, o2h);
  // out = o2 @ Wo
  {
    G3 g3{{o2h, o2h, o2h}, {who, who, who}, 1};
    gemm_bt<<<(S_LEN / 64) * (D_DIM / 128), 256, 0, stream>>>(g3, out, S_LEN, D_DIM, D_DIM);
  }
}

// Round 19
// 332.756 us; speedup vs baseline: 1.0932x; 1.0260x over previous
//
#include <hip/hip_runtime.h>
#include <hip/hip_bf16.h>
#include <math.h>

#define S_LEN 2048
#define D_DIM 2048
#define NH 32
#define HD 64
#define CS 256
#define NCH 8

typedef __attribute__((ext_vector_type(8))) short bf16x8;
typedef __attribute__((ext_vector_type(4))) short bf16x4;
typedef __attribute__((ext_vector_type(4))) float f32x4;

__device__ __forceinline__ unsigned short f2bf(float f) {
  unsigned int u = __builtin_bit_cast(unsigned int, f);
  unsigned int r = (u + 0x7fffu + ((u >> 16) & 1u)) >> 16;
  return (unsigned short)r;
}
__device__ __forceinline__ float bf2f(unsigned short b) {
  unsigned int u = ((unsigned int)b) << 16;
  return __builtin_bit_cast(float, u);
}

__device__ __forceinline__ f32x4 mfma16(bf16x4 a, bf16x4 b, f32x4 c) {
#if __has_builtin(__builtin_amdgcn_mfma_f32_16x16x16_bf16)
  return __builtin_amdgcn_mfma_f32_16x16x16_bf16(a, b, c, 0, 0, 0);
#elif __has_builtin(__builtin_amdgcn_mfma_f32_16x16x16bf16_1k)
  return __builtin_amdgcn_mfma_f32_16x16x16bf16_1k(a, b, c, 0, 0, 0);
#else
  asm("v_mfma_f32_16x16x16_bf16 %0, %1, %2, %0" : "+v"(c) : "v"(a), "v"(b));
  return c;
#endif
}

__device__ __forceinline__ void gload16(const void* gp, void* lp) {
  __builtin_amdgcn_global_load_lds(
      (const __attribute__((address_space(1))) unsigned int*)gp,
      (__attribute__((address_space(3))) unsigned int*)lp, 16, 0, 0);
}

// ---------------------------------------------------------------------------
// Fused QKVG GEMM, 128x128 tile, BK=64, 32KB LDS, RoPE epilogue on Q,K.
// (R18 form: sched_barrier-bounded per-m rope blocks, VGPR 96.)
// ---------------------------------------------------------------------------
struct QKVG {
  const unsigned short* xh;
  const unsigned short* xl;
  const unsigned short* wh[4];
  const unsigned short* wl[4];
  float* C[4];
  int np[4];
  const float2* rtab;
};

__global__ __launch_bounds__(256) void gemm_qkvg(QKVG g) {
  __shared__ __align__(16) unsigned short Als[128 * 64];
  __shared__ __align__(16) unsigned short Bls[128 * 64];
  const int tid = threadIdx.x;
  const int wid = tid >> 6, lane = tid & 63;
  const int l15 = lane & 15, l4 = lane >> 4;
  const int wr = wid >> 1, wc = wid & 1;
  const int K = D_DIM, N = D_DIM;

  const int bid = blockIdx.x;
  const int xcd = bid & 7;
  const int local = bid >> 3;
  const int c = local >> 6;
  const int idx = local & 63;
  const int out = (xcd & 1) + 2 * c;
  const int grp = xcd >> 1;
  const int row0 = (idx >> 2) << 7;
  const int col0 = ((grp << 2) + (idx & 3)) << 7;

  f32x4 acc[4][4];
#pragma unroll
  for (int m = 0; m < 4; ++m)
#pragma unroll
    for (int n = 0; n < 4; ++n) acc[m][n] = (f32x4){0.f, 0.f, 0.f, 0.f};

  const int np = g.np[out];
  for (int p = 0; p < np; ++p) {
    const unsigned short* Ap = (p == 2) ? g.xl : g.xh;
    const unsigned short* Bp = (p == 1) ? g.wl[out] : g.wh[out];
    for (int kt = 0; kt < K; kt += 64) {
      __syncthreads();
#pragma unroll
      for (int i = 0; i < 4; ++i) {
        const int Lb = i * 4096 + wid * 1024;
        const int L = Lb + lane * 16;
        const int row = L >> 7;
        const int s = (L >> 4) & 7;
        const int cofs = (s ^ (row & 7)) << 3;
        gload16(Ap + (size_t)(row0 + row) * K + kt + cofs, (char*)Als + Lb);
        gload16(Bp + (size_t)(col0 + row) * K + kt + cofs, (char*)Bls + Lb);
      }
      asm volatile("s_waitcnt vmcnt(0)" ::: "memory");
      __syncthreads();
#pragma unroll
      for (int ks = 0; ks < 2; ++ks) {
        bf16x8 af[4], bfr[4];
#pragma unroll
        for (int m = 0; m < 4; ++m) {
          int row = wr * 64 + m * 16 + l15;
          int s = (ks * 4 + l4) ^ (row & 7);
          af[m] = *reinterpret_cast<const bf16x8*>(&Als[row * 64 + s * 8]);
        }
#pragma unroll
        for (int n = 0; n < 4; ++n) {
          int col = wc * 64 + n * 16 + l15;
          int s = (ks * 4 + l4) ^ (col & 7);
          bfr[n] = *reinterpret_cast<const bf16x8*>(&Bls[col * 64 + s * 8]);
        }
#pragma unroll
        for (int m = 0; m < 4; ++m)
#pragma unroll
          for (int n = 0; n < 4; ++n)
            acc[m][n] = __builtin_amdgcn_mfma_f32_16x16x32_bf16(af[m], bfr[n], acc[m][n], 0, 0, 0);
      }
    }
  }

  if (out < 2) {
#pragma unroll
    for (int m = 0; m < 4; ++m) {
      __builtin_amdgcn_sched_barrier(0);
      float2 cs0[4], cs1[4];
#pragma unroll
      for (int r = 0; r < 4; ++r) {
        const int s = row0 + wr * 64 + m * 16 + l4 * 4 + r;
        cs0[r] = g.rtab[s * 32 + l15];
        cs1[r] = g.rtab[s * 32 + 16 + l15];
      }
#pragma unroll
      for (int r = 0; r < 4; ++r) {
        float a1 = acc[m][0][r], a2 = acc[m][2][r];
        acc[m][0][r] = a1 * cs0[r].x - a2 * cs0[r].y;
        acc[m][2][r] = a2 * cs0[r].x + a1 * cs0[r].y;
        float b1 = acc[m][1][r], b2 = acc[m][3][r];
        acc[m][1][r] = b1 * cs1[r].x - b2 * cs1[r].y;
        acc[m][3][r] = b2 * cs1[r].x + b1 * cs1[r].y;
      }
    }
    __builtin_amdgcn_sched_barrier(0);
  }

  float* C = g.C[out];
#pragma unroll
  for (int m = 0; m < 4; ++m)
#pragma unroll
    for (int n = 0; n < 4; ++n)
#pragma unroll
      for (int r = 0; r < 4; ++r)
        C[(size_t)(row0 + wr * 64 + m * 16 + l4 * 4 + r) * N + col0 + wc * 64 + n * 16 + l15] =
            acc[m][n][r];
}

// ---------------------------------------------------------------------------
// bf16 MFMA GEMM 64x128 (out-projection).
// ---------------------------------------------------------------------------
struct G3 {
  const unsigned short* A[3];
  const unsigned short* B[3];
  int np;
};

__global__ __launch_bounds__(256) void gemm_bt(G3 g, float* __restrict__ C,
                                               int M, int N, int K) {
  __shared__ __align__(16) unsigned short Als[64 * 64];
  __shared__ __align__(16) unsigned short Bls[128 * 64];
  const int tid = threadIdx.x;
  const int wid = tid >> 6, lane = tid & 63;
  const int l15 = lane & 15, l4 = lane >> 4;
  const int wr = wid >> 1, wc = wid & 1;
  const int nbx = N >> 7;
  int bid = blockIdx.x;
  const int nwg = gridDim.x;
  if ((nwg & 7) == 0) {
    int q = nwg >> 3;
    bid = (bid & 7) * q + (bid >> 3);
  }
  const int row0 = (bid / nbx) << 6;
  const int col0 = (bid % nbx) << 7;

  f32x4 acc[2][4];
#pragma unroll
  for (int m = 0; m < 2; ++m)
#pragma unroll
    for (int n = 0; n < 4; ++n) acc[m][n] = (f32x4){0.f, 0.f, 0.f, 0.f};

  for (int p = 0; p < g.np; ++p) {
    const unsigned short* Ap = g.A[p];
    const unsigned short* Bp = g.B[p];
    for (int kt = 0; kt < K; kt += 64) {
      __syncthreads();
#pragma unroll
      for (int i = 0; i < 2; ++i) {
        const int Lb = i * 4096 + wid * 1024;
        const int L = Lb + lane * 16;
        const int row = L >> 7;
        const int s = (L >> 4) & 7;
        const int cofs = (s ^ (row & 7)) << 3;
        gload16(Ap + (size_t)(row0 + row) * K + kt + cofs, (char*)Als + Lb);
      }
#pragma unroll
      for (int i = 0; i < 4; ++i) {
        const int Lb = i * 4096 + wid * 1024;
        const int L = Lb + lane * 16;
        const int row = L >> 7;
        const int s = (L >> 4) & 7;
        const int cofs = (s ^ (row & 7)) << 3;
        gload16(Bp + (size_t)(col0 + row) * K + kt + cofs, (char*)Bls + Lb);
      }
      asm volatile("s_waitcnt vmcnt(0)" ::: "memory");
      __syncthreads();
#pragma unroll
      for (int ks = 0; ks < 2; ++ks) {
        bf16x8 af[2], bfr[4];
#pragma unroll
        for (int m = 0; m < 2; ++m) {
          int row = wr * 32 + m * 16 + l15;
          int s = (ks * 4 + l4) ^ (row & 7);
          af[m] = *reinterpret_cast<const bf16x8*>(&Als[row * 64 + s * 8]);
        }
#pragma unroll
        for (int n = 0; n < 4; ++n) {
          int col = wc * 64 + n * 16 + l15;
          int s = (ks * 4 + l4) ^ (col & 7);
          bfr[n] = *reinterpret_cast<const bf16x8*>(&Bls[col * 64 + s * 8]);
        }
#pragma unroll
        for (int m = 0; m < 2; ++m)
#pragma unroll
          for (int n = 0; n < 4; ++n)
            acc[m][n] = __builtin_amdgcn_mfma_f32_16x16x32_bf16(af[m], bfr[n], acc[m][n], 0, 0, 0);
      }
    }
  }

#pragma unroll
  for (int m = 0; m < 2; ++m)
#pragma unroll
    for (int n = 0; n < 4; ++n)
#pragma unroll
      for (int r = 0; r < 4; ++r)
        C[(size_t)(row0 + wr * 32 + m * 16 + l4 * 4 + r) * N + col0 + wc * 64 + n * 16 + l15] =
            acc[m][n][r];
}

// ---------------------------------------------------------------------------
// fp32 SGEMM for W' = Wg1 @ Wg2 (K=64), writing W'^T bf16 directly.
// ---------------------------------------------------------------------------
__global__ __launch_bounds__(256) void sgemm_f32T(const float* __restrict__ A,
                                                  const float* __restrict__ B,
                                                  unsigned short* __restrict__ CT,
                                                  int M, int N, int K) {
  __shared__ float As[8][128];
  __shared__ float Bs[8][128];
  const int tid = threadIdx.x;
  const int row0 = blockIdx.y * 128;
  const int col0 = blockIdx.x * 128;
  const int tm = (tid / 16) * 8;
  const int tn = (tid % 16) * 8;
  const int arow = tid >> 1;
  const int acol = (tid & 1) * 4;
  const int brow = tid >> 5;
  const int bcol = (tid & 31) * 4;

  float acc[8][8];
#pragma unroll
  for (int i = 0; i < 8; ++i)
#pragma unroll
    for (int j = 0; j < 8; ++j) acc[i][j] = 0.f;

  for (int k0 = 0; k0 < K; k0 += 8) {
    float4 av = make_float4(0.f, 0.f, 0.f, 0.f);
    if (row0 + arow < M) {
      int kb = k0 + acol;
      av = *reinterpret_cast<const float4*>(&A[(size_t)(row0 + arow) * K + kb]);
    }
    As[acol + 0][arow] = av.x;
    As[acol + 1][arow] = av.y;
    As[acol + 2][arow] = av.z;
    As[acol + 3][arow] = av.w;
    float4 bv = make_float4(0.f, 0.f, 0.f, 0.f);
    if (k0 + brow < K) {
      bv = *reinterpret_cast<const float4*>(&B[(size_t)(k0 + brow) * N + col0 + bcol]);
    }
    *reinterpret_cast<float4*>(&Bs[brow][bcol]) = bv;
    __syncthreads();
#pragma unroll
    for (int kk = 0; kk < 8; ++kk) {
      float a[8], b[8];
      *reinterpret_cast<float4*>(&a[0]) = *reinterpret_cast<const float4*>(&As[kk][tm]);
      *reinterpret_cast<float4*>(&a[4]) = *reinterpret_cast<const float4*>(&As[kk][tm + 4]);
      *reinterpret_cast<float4*>(&b[0]) = *reinterpret_cast<const float4*>(&Bs[kk][tn]);
      *reinterpret_cast<float4*>(&b[4]) = *reinterpret_cast<const float4*>(&Bs[kk][tn + 4]);
#pragma unroll
      for (int i = 0; i < 8; ++i)
#pragma unroll
        for (int j = 0; j < 8; ++j) acc[i][j] = fmaf(a[i], b[j], acc[i][j]);
    }
    __syncthreads();
  }
#pragma unroll
  for (int j = 0; j < 8; ++j) {
    const int n = col0 + tn + j;
    ushort4 u0 = make_ushort4(f2bf(acc[0][j]), f2bf(acc[1][j]), f2bf(acc[2][j]), f2bf(acc[3][j]));
    ushort4 u1 = make_ushort4(f2bf(acc[4][j]), f2bf(acc[5][j]), f2bf(acc[6][j]), f2bf(acc[7][j]));
    *reinterpret_cast<ushort4*>(&CT[(size_t)n * M + row0 + tm]) = u0;
    *reinterpret_cast<ushort4*>(&CT[(size_t)n * M + row0 + tm + 4]) = u1;
  }
}

// ---------------------------------------------------------------------------
// x fp32 -> xh, xl bf16; blocks 0..255 also fill the RoPE cos/sin table.
// ---------------------------------------------------------------------------
__global__ __launch_bounds__(256) void repack_x_hl(const float* __restrict__ x,
                                                   unsigned short* __restrict__ xh,
                                                   unsigned short* __restrict__ xl,
                                                   float2* __restrict__ rtab) {
  int i = (blockIdx.x * 256 + threadIdx.x) * 4;
  float4 v = *reinterpret_cast<const float4*>(&x[i]);
  float f[4] = {v.x, v.y, v.z, v.w};
  unsigned short h[4], l[4];
#pragma unroll
  for (int j = 0; j < 4; ++j) {
    h[j] = f2bf(f[j]);
    l[j] = f2bf(f[j] - bf2f(h[j]));
  }
  *reinterpret_cast<ushort4*>(&xh[i]) = make_ushort4(h[0], h[1], h[2], h[3]);
  *reinterpret_cast<ushort4*>(&xl[i]) = make_ushort4(l[0], l[1], l[2], l[3]);
  // rope table: 65536 entries = first 256 blocks x 256 threads
  if (blockIdx.x < 256) {
    int idx = blockIdx.x * 256 + threadIdx.x;
    int d = idx & 31;
    int s = idx >> 5;
    float inv = 1.0f / powf(10000.0f, (float)d * (1.0f / 32.0f));
    float fr = (float)s * inv;
    rtab[idx] = make_float2(cosf(fr), sinf(fr));
  }
}

// ---------------------------------------------------------------------------
// Fused 4-weight transpose repack (Wq, Wk with lo; Wv, Wo hi-only).
// ---------------------------------------------------------------------------
struct RT4 {
  const float* W[4];
  unsigned short* hiT[4];
  unsigned short* loT[4];
  int has_lo[4];
};

__global__ __launch_bounds__(256) void repack_T4(RT4 a) {
  __shared__ float t[64][65];
  const int wsel = blockIdx.z;
  const float* W = a.W[wsel];
  unsigned short* hiT = a.hiT[wsel];
  unsigned short* loT = a.loT[wsel];
  const int has_lo = a.has_lo[wsel];
  const int k0 = blockIdx.y * 64, n0 = blockIdx.x * 64;
  const int tid = threadIdx.x;
  const int c = tid & 63, rr = tid >> 6;
#pragma unroll
  for (int r = 0; r < 16; ++r) {
    int kr = r * 4 + rr;
    t[kr][c] = W[(size_t)(k0 + kr) * D_DIM + n0 + c];
  }
  __syncthreads();
#pragma unroll
  for (int r = 0; r < 16; ++r) {
    int n = r * 4 + rr;
    float f = t[c][n];
    unsigned short hb = f2bf(f);
    hiT[(size_t)(n0 + n) * D_DIM + k0 + c] = hb;
    if (has_lo) loT[(size_t)(n0 + n) * D_DIM + k0 + c] = f2bf(f - bf2f(hb));
  }
}

// ---------------------------------------------------------------------------
// Chunk means of k (k already roped by gemm_qkvg epilogue).
// ---------------------------------------------------------------------------
__global__ __launch_bounds__(256) void chunk_mean(const float* __restrict__ k,
                                                  float* __restrict__ kg) {
  int idx = blockIdx.x * 256 + threadIdx.x;
  if (idx >= NCH * NH * HD) return;
  int c = idx / (NH * HD);
  int hd = idx % (NH * HD);
  float sum = 0.f;
  for (int t = 0; t < CS; ++t) sum += k[(size_t)(c * CS + t) * (NH * HD) + hd];
  kg[idx] = sum * (1.0f / CS);
}

// ---------------------------------------------------------------------------
// Gate + top-3-past chunk selection (fp32; q already roped).
// ---------------------------------------------------------------------------
__global__ __launch_bounds__(256) void gate_topk(const float* __restrict__ q,
                                                 const float* __restrict__ kg,
                                                 int* __restrict__ amask) {
  int wid = threadIdx.x >> 6;
  int lane = threadIdx.x & 63;
  int s = blockIdx.x * 4 + wid;
  int h = blockIdx.y;
  int myc = s >> 8;
  float qd = q[((size_t)s * NH + h) * HD + lane];
  float g[NCH];
#pragma unroll
  for (int c = 0; c < NCH; ++c) {
    float p = qd * kg[((size_t)c * NH + h) * HD + lane];
#pragma unroll
    for (int off = 32; off; off >>= 1) p += __shfl_xor(p, off);
    g[c] = p;
  }
  int chosen = 0;
#pragma unroll
  for (int pick = 0; pick < 3; ++pick) {
    float best = -INFINITY;
    int bi = -1;
#pragma unroll
    for (int c = 0; c < NCH; ++c) {
      if (c < myc && !((chosen >> c) & 1) && g[c] > best) {
        best = g[c];
        bi = c;
      }
    }
    if (bi >= 0) chosen |= (1 << bi);
  }
  int mask = chosen | (1 << myc);
  if (lane == 0) amask[h * S_LEN + s] = mask;
}

// ---------------------------------------------------------------------------
// K,V fp32 [s][h][d] -> fragment-major bf16 (one kernel, both outputs).
// ---------------------------------------------------------------------------
__global__ __launch_bounds__(256) void repack_kvf(const float* __restrict__ k,
                                                  const float* __restrict__ v,
                                                  unsigned short* __restrict__ khf,
                                                  unsigned short* __restrict__ vhf) {
  __shared__ float tk[64][68];
  __shared__ float tv[64][68];
  const int t = blockIdx.x;
  const int h = blockIdx.y;
  const int tid = threadIdx.x;
  const int t0 = t * 64;
  {
    const int r = tid >> 2, c4 = (tid & 3) * 16;
    const float* sk = &k[((size_t)(t0 + r) * NH + h) * HD + c4];
    const float* sv = &v[((size_t)(t0 + r) * NH + h) * HD + c4];
#pragma unroll
    for (int qd = 0; qd < 4; ++qd) {
      *reinterpret_cast<float4*>(&tk[r][c4 + qd * 4]) =
          *reinterpret_cast<const float4*>(sk + qd * 4);
      *reinterpret_cast<float4*>(&tv[r][c4 + qd * 4]) =
          *reinterpret_cast<const float4*>(sv + qd * 4);
    }
  }
  __syncthreads();
  const int w = tid >> 6, l = tid & 63;
  const int l15 = l & 15, g = l >> 4;
  unsigned short* obk = khf + (((size_t)h * 32 + t) * 8) * 512;
  unsigned short* obv = vhf + (((size_t)h * 32 + t) * 8) * 512;
#pragma unroll
  for (int ff = 0; ff < 2; ++ff) {
    const int f = 2 * w + ff;
    {
      const int st = f >> 1, half = f & 1;
      const float* rp = &tk[st * 16 + l15][g * 8 + half * 32];
      ushort4 u0 = make_ushort4(f2bf(rp[0]), f2bf(rp[1]), f2bf(rp[2]), f2bf(rp[3]));
      ushort4 u1 = make_ushort4(f2bf(rp[4]), f2bf(rp[5]), f2bf(rp[6]), f2bf(rp[7]));
      *reinterpret_cast<ushort4*>(obk + (size_t)f * 512 + l * 8) = u0;
      *reinterpret_cast<ushort4*>(obk + (size_t)f * 512 + l * 8 + 4) = u1;
    }
    {
      const int st = f >> 1, p = f & 1;
      unsigned short u[8];
#pragma unroll
      for (int e = 0; e < 8; ++e) {
        const int cb = 2 * p + (e >> 2);
        const int j = e & 3;
        u[e] = f2bf(tv[st * 16 + 4 * g + j][cb * 16 + l15]);
      }
      *reinterpret_cast<ushort4*>(obv + (size_t)f * 512 + l * 8) =
          make_ushort4(u[0], u[1], u[2], u[3]);
      *reinterpret_cast<ushort4*>(obv + (size_t)f * 512 + l * 8 + 4) =
          make_ushort4(u[4], u[5], u[6], u[7]);
    }
  }
}

// ---------------------------------------------------------------------------
// MFMA flash attention, split-K across 4 waves, fragment-major K/V loads.
// Epilogue now fuses RMS-norm + sigmoid gate and emits bf16 o2h directly
// (postproc kernel removed; no fp32 o round-trip).
// ---------------------------------------------------------------------------
__global__ __launch_bounds__(256) void attn_mfma(const float* __restrict__ q,
                                                 const unsigned short* __restrict__ khf,
                                                 const unsigned short* __restrict__ vhf,
                                                 const int* __restrict__ amask,
                                                 const float* __restrict__ gbuf,
                                                 const float* __restrict__ onw,
                                                 unsigned short* __restrict__ o2h) {
  const int B = blockIdx.x;
  const int xcd = B & 7;
  const int jb = B >> 3;
  const int h = xcd + ((jb >> 7) << 3);
  const int s0 = (jb & 127) << 4;
  const int tid = threadIdx.x;
  const int wid = tid >> 6;
  const int lane = tid & 63;
  const int l15 = lane & 15, g = lane >> 4;
  const int myS = s0 + l15;
  const int myc = s0 >> 8;
  const int ktm = (s0 & (CS - 1)) >> 6;

  __shared__ float lm[4][16];
  __shared__ float ll[4][16];
  __shared__ float lacc[4][16][64];
  __shared__ float lss[4][16];

  const float* qrow = q + ((size_t)myS * NH + h) * HD;
  bf16x8 qf[2];
#pragma unroll
  for (int hf = 0; hf < 2; ++hf)
#pragma unroll
    for (int jj = 0; jj < 8; ++jj)
      qf[hf][jj] = (short)f2bf(qrow[hf * 32 + g * 8 + jj] * 0.125f);

  int mymask = amask[h * S_LEN + myS];
  int wmask = mymask;
  wmask |= __shfl_xor(wmask, 1);
  wmask |= __shfl_xor(wmask, 2);
  wmask |= __shfl_xor(wmask, 4);
  wmask |= __shfl_xor(wmask, 8);
  const int pmask = wmask & ~(1 << myc);
  const int ntot = (ktm + 1) + 4 * __popc(pmask);

  auto DEC = [&](int j) -> int {
    if (j <= ktm) return ((s0 & ~255) + (j << 6)) | (1 << 16);
    int jj = j - ktm - 1;
    int mm = pmask;
    int drop = jj >> 2;
    for (int b = 0; b < drop; ++b) mm &= mm - 1;
    int c = __ffs(mm) - 1;
    return ((c << 8) + ((jj & 3) << 6)) | (((mymask >> c) & 1) << 16);
  };

  const unsigned short* khh = khf + (((size_t)h * 32) << 12);
  const unsigned short* vhh = vhf + (((size_t)h * 32) << 12);

  bf16x8 kr[4][2];
  auto LOADK = [&](int t0) {
    const unsigned short* tb = khh + ((size_t)(t0 >> 6) << 12) + lane * 8;
#pragma unroll
    for (int f = 0; f < 8; ++f)
      kr[f >> 1][f & 1] = *reinterpret_cast<const bf16x8*>(tb + f * 512);
  };

  float m = -1e30f, lsum = 0.f;
  f32x4 accv[4];
#pragma unroll
  for (int i = 0; i < 4; ++i) accv[i] = (f32x4){0.f, 0.f, 0.f, 0.f};

  if (wid < ntot) LOADK(DEC(wid) & 0xFFFF);

#pragma unroll
  for (int i = 0; i < 8; ++i) {
    const int j = wid + (i << 2);
    if (j < ntot) {
      const int ent = DEC(j);
      const int t0 = ent & 0xFFFF;
      const bool lane_on = (ent >> 16) != 0;
      const bool diag = (j == ktm);

      const unsigned short* vtb = vhh + ((size_t)(t0 >> 6) << 12) + lane * 8;
      bf16x4 vb[4][4];
#pragma unroll
      for (int fp = 0; fp < 8; ++fp) {
        bf16x8 wv = *reinterpret_cast<const bf16x8*>(vtb + fp * 512);
        const int st = fp >> 1, pp = fp & 1;
#pragma unroll
        for (int jj = 0; jj < 4; ++jj) {
          vb[st][2 * pp][jj] = wv[jj];
          vb[st][2 * pp + 1][jj] = wv[4 + jj];
        }
      }

      float p[16];
      __builtin_amdgcn_s_setprio(1);
#pragma unroll
      for (int st = 0; st < 4; ++st) {
        f32x4 d = (f32x4){0.f, 0.f, 0.f, 0.f};
        d = __builtin_amdgcn_mfma_f32_16x16x32_bf16(kr[st][0], qf[0], d, 0, 0, 0);
        d = __builtin_amdgcn_mfma_f32_16x16x32_bf16(kr[st][1], qf[1], d, 0, 0, 0);
#pragma unroll
        for (int r = 0; r < 4; ++r) {
          bool ok = lane_on && (!diag || (t0 + st * 16 + 4 * g + r <= myS));
          p[st * 4 + r] = ok ? d[r] : -1e30f;
        }
      }
      __builtin_amdgcn_s_setprio(0);

      if (j + 4 < ntot) LOADK(DEC(j + 4) & 0xFFFF);

      float mt = -1e30f;
#pragma unroll
      for (int ii = 0; ii < 16; ++ii) mt = fmaxf(mt, p[ii]);
      mt = fmaxf(mt, __shfl_xor(mt, 16));
      mt = fmaxf(mt, __shfl_xor(mt, 32));

      const float mnew = fmaxf(m, mt);
      const float corr = __expf(m - mnew);
      float ps = 0.f;
#pragma unroll
      for (int ii = 0; ii < 16; ++ii) {
        float pv = (p[ii] > -1e29f) ? __expf(p[ii] - mnew) : 0.f;
        p[ii] = pv;
        ps += pv;
      }
      ps += __shfl_xor(ps, 16);
      ps += __shfl_xor(ps, 32);
      lsum = lsum * corr + ps;
      m = mnew;

#pragma unroll
      for (int r = 0; r < 4; ++r) {
        float cr = __shfl(corr, 4 * g + r);
#pragma unroll
        for (int cb = 0; cb < 4; ++cb) accv[cb][r] *= cr;
      }

      __builtin_amdgcn_s_setprio(1);
#pragma unroll
      for (int st = 0; st < 4; ++st) {
        bf16x4 pa;
#pragma unroll
        for (int jj = 0; jj < 4; ++jj) pa[jj] = (short)f2bf(p[st * 4 + jj]);
#pragma unroll
        for (int cb = 0; cb < 4; ++cb)
          accv[cb] = mfma16(pa, vb[st][cb], accv[cb]);
      }
      __builtin_amdgcn_s_setprio(0);
    }
  }

#pragma unroll
  for (int cb = 0; cb < 4; ++cb)
#pragma unroll
    for (int r = 0; r < 4; ++r) lacc[wid][cb * 4 + r][lane] = accv[cb][r];
  if (lane < 16) {
    lm[wid][lane] = m;
    ll[wid][lane] = lsum;
  }
  __syncthreads();

  // ---- merge: wave `wid` produces dim-block cb = wid ----
  float outv[4];
#pragma unroll
  for (int r = 0; r < 4; ++r) {
    const int row = 4 * g + r;
    float m0 = lm[0][row], m1 = lm[1][row], m2 = lm[2][row], m3 = lm[3][row];
    float mt = fmaxf(fmaxf(m0, m1), fmaxf(m2, m3));
    float e0 = __expf(m0 - mt), e1 = __expf(m1 - mt);
    float e2 = __expf(m2 - mt), e3 = __expf(m3 - mt);
    float ltot = ll[0][row] * e0 + ll[1][row] * e1 + ll[2][row] * e2 + ll[3][row] * e3;
    float a = lacc[0][wid * 4 + r][lane] * e0 + lacc[1][wid * 4 + r][lane] * e1 +
              lacc[2][wid * 4 + r][lane] * e2 + lacc[3][wid * 4 + r][lane] * e3;
    outv[r] = a / ltot;
  }

  // ---- fused RMS-norm + sigmoid gate ----
  // Per-row sum of squares: reduce over 16 dim-lanes (same g group), then
  // across the 4 waves (dim blocks) via lss.
  float ssr[4];
#pragma unroll
  for (int r = 0; r < 4; ++r) {
    float ss = outv[r] * outv[r];
#pragma unroll
    for (int off = 1; off < 16; off <<= 1) ss += __shfl_xor(ss, off);
    ssr[r] = ss;
  }
  if (l15 == 0) {
#pragma unroll
    for (int r = 0; r < 4; ++r) lss[wid][4 * g + r] = ssr[r];
  }
  __syncthreads();
  const float wgt = onw[wid * 16 + l15];
#pragma unroll
  for (int r = 0; r < 4; ++r) {
    const int row = 4 * g + r;
    float sstot = lss[0][row] + lss[1][row] + lss[2][row] + lss[3][row];
    float rms = rsqrtf(sstot * (1.0f / HD) + 1e-6f);
    float gv = gbuf[(size_t)(s0 + row) * D_DIM + h * HD + wid * 16 + l15];
    float sig = 1.0f / (1.0f + expf(-gv));
    o2h[(size_t)(s0 + row) * D_DIM + h * HD + wid * 16 + l15] =
        f2bf(outv[r] * rms * wgt * sig);
  }
}

// ---------------------------------------------------------------------------
extern "C" void kernel_launch(void* const* d_in, const int* in_sizes, int n_in,
                              void* d_out, int out_size, void* d_ws, size_t ws_size,
                              hipStream_t stream) {
  const float* x   = (const float*)d_in[0];
  const float* Wq  = (const float*)d_in[1];
  const float* Wk  = (const float*)d_in[2];
  const float* Wv  = (const float*)d_in[3];
  const float* Wo  = (const float*)d_in[4];
  const float* Wg1 = (const float*)d_in[5];
  const float* Wg2 = (const float*)d_in[6];
  const float* onw = (const float*)d_in[7];
  float* out = (float*)d_out;

  const size_t BIG = (size_t)S_LEN * D_DIM;  // 4M elements
  float* q    = (float*)d_ws;
  float* k    = q + BIG;
  float* v    = k + BIG;
  float* gbuf = v + BIG;
  float* kg   = gbuf + BIG;                    // NCH*NH*HD
  int* amask  = (int*)(kg + NCH * NH * HD);    // NH*S
  float2* rtab = (float2*)(amask + NH * S_LEN);  // S*32 float2
  unsigned short* xh  = (unsigned short*)(rtab + S_LEN * 32);
  unsigned short* xl  = xh + BIG;
  unsigned short* whq = xl + BIG;
  unsigned short* wlq = whq + BIG;
  unsigned short* whk = wlq + BIG;
  unsigned short* wlk = whk + BIG;
  unsigned short* whv = wlk + BIG;
  unsigned short* whg = whv + BIG;
  unsigned short* who = whg + BIG;
  unsigned short* khf = who + BIG;
  unsigned short* vhf = khf + BIG;
  unsigned short* o2h = vhf + BIG;

  // Split x into hi/lo bf16 (+ rope table in blocks 0..255)
  repack_x_hl<<<(int)(BIG / 4 / 256), 256, 0, stream>>>(x, xh, xl, rtab);
  // Fused weight repacks: Wq(lo), Wk(lo), Wv, Wo
  {
    RT4 rt;
    rt.W[0] = Wq; rt.hiT[0] = whq; rt.loT[0] = wlq; rt.has_lo[0] = 1;
    rt.W[1] = Wk; rt.hiT[1] = whk; rt.loT[1] = wlk; rt.has_lo[1] = 1;
    rt.W[2] = Wv; rt.hiT[2] = whv; rt.loT[2] = whv; rt.has_lo[2] = 0;
    rt.W[3] = Wo; rt.hiT[3] = who; rt.loT[3] = who; rt.has_lo[3] = 0;
    repack_T4<<<dim3(32, 32, 4), 256, 0, stream>>>(rt);
  }
  // W' = Wg1 @ Wg2 -> whg (bf16 transposed, direct)
  sgemm_f32T<<<dim3(16, 16), 256, 0, stream>>>(Wg1, Wg2, whg, D_DIM, D_DIM, HD);

  // Fused Q(3) K(3) V(1) G(1) projections + RoPE epilogue on Q,K
  {
    QKVG gg;
    gg.xh = xh; gg.xl = xl;
    gg.wh[0] = whq; gg.wh[1] = whk; gg.wh[2] = whv; gg.wh[3] = whg;
    gg.wl[0] = wlq; gg.wl[1] = wlk; gg.wl[2] = nullptr; gg.wl[3] = nullptr;
    gg.C[0] = q; gg.C[1] = k; gg.C[2] = v; gg.C[3] = gbuf;
    gg.np[0] = 3; gg.np[1] = 3; gg.np[2] = 1; gg.np[3] = 1;
    gg.rtab = rtab;
    gemm_qkvg<<<1024, 256, 0, stream>>>(gg);
  }

  // Chunk means + gating (fp32; q,k already roped)
  chunk_mean<<<(NCH * NH * HD + 255) / 256, 256, 0, stream>>>(k, kg);
  gate_topk<<<dim3(S_LEN / 4, NH), 256, 0, stream>>>(q, kg, amask);
  // Fragment-major K/V repack (fused)
  repack_kvf<<<dim3(S_LEN / 64, NH), 256, 0, stream>>>(k, v, khf, vhf);
  // Attention + fused RMS-norm/sigmoid -> bf16 o2h
  attn_mfma<<<(S_LEN / 16) * NH, 256, 0, stream>>>(q, khf, vhf, amask, gbuf, onw, o2h);
  // out = o2 @ Wo
  {
    G3 g3{{o2h, o2h, o2h}, {who, who, who}, 1};
    gemm_bt<<<(S_LEN / 64) * (D_DIM / 128), 256, 0, stream>>>(g3, out, S_LEN, D_DIM, D_DIM);
  }
}

// Round 20
// 325.476 us; speedup vs baseline: 1.1176x; 1.0224x over previous
//
#include <hip/hip_runtime.h>
#include <hip/hip_bf16.h>
#include <math.h>

#define S_LEN 2048
#define D_DIM 2048
#define NH 32
#define HD 64
#define CS 256
#define NCH 8

typedef __attribute__((ext_vector_type(8))) short bf16x8;
typedef __attribute__((ext_vector_type(4))) short bf16x4;
typedef __attribute__((ext_vector_type(4))) float f32x4;

__device__ __forceinline__ unsigned short f2bf(float f) {
  unsigned int u = __builtin_bit_cast(unsigned int, f);
  unsigned int r = (u + 0x7fffu + ((u >> 16) & 1u)) >> 16;
  return (unsigned short)r;
}
__device__ __forceinline__ float bf2f(unsigned short b) {
  unsigned int u = ((unsigned int)b) << 16;
  return __builtin_bit_cast(float, u);
}

__device__ __forceinline__ f32x4 mfma16(bf16x4 a, bf16x4 b, f32x4 c) {
#if __has_builtin(__builtin_amdgcn_mfma_f32_16x16x16_bf16)
  return __builtin_amdgcn_mfma_f32_16x16x16_bf16(a, b, c, 0, 0, 0);
#elif __has_builtin(__builtin_amdgcn_mfma_f32_16x16x16bf16_1k)
  return __builtin_amdgcn_mfma_f32_16x16x16bf16_1k(a, b, c, 0, 0, 0);
#else
  asm("v_mfma_f32_16x16x16_bf16 %0, %1, %2, %0" : "+v"(c) : "v"(a), "v"(b));
  return c;
#endif
}

__device__ __forceinline__ void gload16(const void* gp, void* lp) {
  __builtin_amdgcn_global_load_lds(
      (const __attribute__((address_space(1))) unsigned int*)gp,
      (__attribute__((address_space(3))) unsigned int*)lp, 16, 0, 0);
}

// ---------------------------------------------------------------------------
// Fused QKVG GEMM, 128x128 tile, BK=64, 32KB LDS, RoPE epilogue on Q,K.
// (R18 form: sched_barrier-bounded per-m rope blocks, VGPR 96.)
// ---------------------------------------------------------------------------
struct QKVG {
  const unsigned short* xh;
  const unsigned short* xl;
  const unsigned short* wh[4];
  const unsigned short* wl[4];
  float* C[4];
  int np[4];
  const float2* rtab;
};

__global__ __launch_bounds__(256) void gemm_qkvg(QKVG g) {
  __shared__ __align__(16) unsigned short Als[128 * 64];
  __shared__ __align__(16) unsigned short Bls[128 * 64];
  const int tid = threadIdx.x;
  const int wid = tid >> 6, lane = tid & 63;
  const int l15 = lane & 15, l4 = lane >> 4;
  const int wr = wid >> 1, wc = wid & 1;
  const int K = D_DIM, N = D_DIM;

  const int bid = blockIdx.x;
  const int xcd = bid & 7;
  const int local = bid >> 3;
  const int c = local >> 6;
  const int idx = local & 63;
  const int out = (xcd & 1) + 2 * c;
  const int grp = xcd >> 1;
  const int row0 = (idx >> 2) << 7;
  const int col0 = ((grp << 2) + (idx & 3)) << 7;

  f32x4 acc[4][4];
#pragma unroll
  for (int m = 0; m < 4; ++m)
#pragma unroll
    for (int n = 0; n < 4; ++n) acc[m][n] = (f32x4){0.f, 0.f, 0.f, 0.f};

  const int np = g.np[out];
  for (int p = 0; p < np; ++p) {
    const unsigned short* Ap = (p == 2) ? g.xl : g.xh;
    const unsigned short* Bp = (p == 1) ? g.wl[out] : g.wh[out];
    for (int kt = 0; kt < K; kt += 64) {
      __syncthreads();
#pragma unroll
      for (int i = 0; i < 4; ++i) {
        const int Lb = i * 4096 + wid * 1024;
        const int L = Lb + lane * 16;
        const int row = L >> 7;
        const int s = (L >> 4) & 7;
        const int cofs = (s ^ (row & 7)) << 3;
        gload16(Ap + (size_t)(row0 + row) * K + kt + cofs, (char*)Als + Lb);
        gload16(Bp + (size_t)(col0 + row) * K + kt + cofs, (char*)Bls + Lb);
      }
      asm volatile("s_waitcnt vmcnt(0)" ::: "memory");
      __syncthreads();
#pragma unroll
      for (int ks = 0; ks < 2; ++ks) {
        bf16x8 af[4], bfr[4];
#pragma unroll
        for (int m = 0; m < 4; ++m) {
          int row = wr * 64 + m * 16 + l15;
          int s = (ks * 4 + l4) ^ (row & 7);
          af[m] = *reinterpret_cast<const bf16x8*>(&Als[row * 64 + s * 8]);
        }
#pragma unroll
        for (int n = 0; n < 4; ++n) {
          int col = wc * 64 + n * 16 + l15;
          int s = (ks * 4 + l4) ^ (col & 7);
          bfr[n] = *reinterpret_cast<const bf16x8*>(&Bls[col * 64 + s * 8]);
        }
#pragma unroll
        for (int m = 0; m < 4; ++m)
#pragma unroll
          for (int n = 0; n < 4; ++n)
            acc[m][n] = __builtin_amdgcn_mfma_f32_16x16x32_bf16(af[m], bfr[n], acc[m][n], 0, 0, 0);
      }
    }
  }

  if (out < 2) {
#pragma unroll
    for (int m = 0; m < 4; ++m) {
      __builtin_amdgcn_sched_barrier(0);
      float2 cs0[4], cs1[4];
#pragma unroll
      for (int r = 0; r < 4; ++r) {
        const int s = row0 + wr * 64 + m * 16 + l4 * 4 + r;
        cs0[r] = g.rtab[s * 32 + l15];
        cs1[r] = g.rtab[s * 32 + 16 + l15];
      }
#pragma unroll
      for (int r = 0; r < 4; ++r) {
        float a1 = acc[m][0][r], a2 = acc[m][2][r];
        acc[m][0][r] = a1 * cs0[r].x - a2 * cs0[r].y;
        acc[m][2][r] = a2 * cs0[r].x + a1 * cs0[r].y;
        float b1 = acc[m][1][r], b2 = acc[m][3][r];
        acc[m][1][r] = b1 * cs1[r].x - b2 * cs1[r].y;
        acc[m][3][r] = b2 * cs1[r].x + b1 * cs1[r].y;
      }
    }
    __builtin_amdgcn_sched_barrier(0);
  }

  float* C = g.C[out];
#pragma unroll
  for (int m = 0; m < 4; ++m)
#pragma unroll
    for (int n = 0; n < 4; ++n)
#pragma unroll
      for (int r = 0; r < 4; ++r)
        C[(size_t)(row0 + wr * 64 + m * 16 + l4 * 4 + r) * N + col0 + wc * 64 + n * 16 + l15] =
            acc[m][n][r];
}

// ---------------------------------------------------------------------------
// bf16 MFMA GEMM 64x128 (out-projection).
// ---------------------------------------------------------------------------
struct G3 {
  const unsigned short* A[3];
  const unsigned short* B[3];
  int np;
};

__global__ __launch_bounds__(256) void gemm_bt(G3 g, float* __restrict__ C,
                                               int M, int N, int K) {
  __shared__ __align__(16) unsigned short Als[64 * 64];
  __shared__ __align__(16) unsigned short Bls[128 * 64];
  const int tid = threadIdx.x;
  const int wid = tid >> 6, lane = tid & 63;
  const int l15 = lane & 15, l4 = lane >> 4;
  const int wr = wid >> 1, wc = wid & 1;
  const int nbx = N >> 7;
  int bid = blockIdx.x;
  const int nwg = gridDim.x;
  if ((nwg & 7) == 0) {
    int q = nwg >> 3;
    bid = (bid & 7) * q + (bid >> 3);
  }
  const int row0 = (bid / nbx) << 6;
  const int col0 = (bid % nbx) << 7;

  f32x4 acc[2][4];
#pragma unroll
  for (int m = 0; m < 2; ++m)
#pragma unroll
    for (int n = 0; n < 4; ++n) acc[m][n] = (f32x4){0.f, 0.f, 0.f, 0.f};

  for (int p = 0; p < g.np; ++p) {
    const unsigned short* Ap = g.A[p];
    const unsigned short* Bp = g.B[p];
    for (int kt = 0; kt < K; kt += 64) {
      __syncthreads();
#pragma unroll
      for (int i = 0; i < 2; ++i) {
        const int Lb = i * 4096 + wid * 1024;
        const int L = Lb + lane * 16;
        const int row = L >> 7;
        const int s = (L >> 4) & 7;
        const int cofs = (s ^ (row & 7)) << 3;
        gload16(Ap + (size_t)(row0 + row) * K + kt + cofs, (char*)Als + Lb);
      }
#pragma unroll
      for (int i = 0; i < 4; ++i) {
        const int Lb = i * 4096 + wid * 1024;
        const int L = Lb + lane * 16;
        const int row = L >> 7;
        const int s = (L >> 4) & 7;
        const int cofs = (s ^ (row & 7)) << 3;
        gload16(Bp + (size_t)(col0 + row) * K + kt + cofs, (char*)Bls + Lb);
      }
      asm volatile("s_waitcnt vmcnt(0)" ::: "memory");
      __syncthreads();
#pragma unroll
      for (int ks = 0; ks < 2; ++ks) {
        bf16x8 af[2], bfr[4];
#pragma unroll
        for (int m = 0; m < 2; ++m) {
          int row = wr * 32 + m * 16 + l15;
          int s = (ks * 4 + l4) ^ (row & 7);
          af[m] = *reinterpret_cast<const bf16x8*>(&Als[row * 64 + s * 8]);
        }
#pragma unroll
        for (int n = 0; n < 4; ++n) {
          int col = wc * 64 + n * 16 + l15;
          int s = (ks * 4 + l4) ^ (col & 7);
          bfr[n] = *reinterpret_cast<const bf16x8*>(&Bls[col * 64 + s * 8]);
        }
#pragma unroll
        for (int m = 0; m < 2; ++m)
#pragma unroll
          for (int n = 0; n < 4; ++n)
            acc[m][n] = __builtin_amdgcn_mfma_f32_16x16x32_bf16(af[m], bfr[n], acc[m][n], 0, 0, 0);
      }
    }
  }

#pragma unroll
  for (int m = 0; m < 2; ++m)
#pragma unroll
    for (int n = 0; n < 4; ++n)
#pragma unroll
      for (int r = 0; r < 4; ++r)
        C[(size_t)(row0 + wr * 32 + m * 16 + l4 * 4 + r) * N + col0 + wc * 64 + n * 16 + l15] =
            acc[m][n][r];
}

// ---------------------------------------------------------------------------
// fp32 SGEMM for W' = Wg1 @ Wg2 (K=64), writing W'^T bf16 directly.
// 64x128 tile -> 512 blocks (2/CU; the 128x128 version was 1/CU and
// latency-bound at K=64). Per-output accumulation order unchanged.
// ---------------------------------------------------------------------------
__global__ __launch_bounds__(256) void sgemm_f32T(const float* __restrict__ A,
                                                  const float* __restrict__ B,
                                                  unsigned short* __restrict__ CT,
                                                  int M, int N, int K) {
  __shared__ float As[8][64];
  __shared__ float Bs[8][128];
  const int tid = threadIdx.x;
  const int row0 = blockIdx.y * 64;
  const int col0 = blockIdx.x * 128;
  const int tm = (tid >> 5) * 8;        // 8 row-groups of 8 rows
  const int tn = (tid & 31) * 4;        // 32 col-groups of 4 cols
  const int arow = tid >> 2;            // 0..63
  const int acol = (tid & 3) * 2;       // 0,2,4,6
  const int brow = tid >> 5;            // 0..7
  const int bcol = (tid & 31) * 4;      // 0..124

  float acc[8][4];
#pragma unroll
  for (int i = 0; i < 8; ++i)
#pragma unroll
    for (int j = 0; j < 4; ++j) acc[i][j] = 0.f;

  for (int k0 = 0; k0 < K; k0 += 8) {
    float2 av = *reinterpret_cast<const float2*>(&A[(size_t)(row0 + arow) * K + k0 + acol]);
    As[acol + 0][arow] = av.x;
    As[acol + 1][arow] = av.y;
    float4 bv = *reinterpret_cast<const float4*>(&B[(size_t)(k0 + brow) * N + col0 + bcol]);
    *reinterpret_cast<float4*>(&Bs[brow][bcol]) = bv;
    __syncthreads();
#pragma unroll
    for (int kk = 0; kk < 8; ++kk) {
      float a[8], b[4];
      *reinterpret_cast<float4*>(&a[0]) = *reinterpret_cast<const float4*>(&As[kk][tm]);
      *reinterpret_cast<float4*>(&a[4]) = *reinterpret_cast<const float4*>(&As[kk][tm + 4]);
      *reinterpret_cast<float4*>(&b[0]) = *reinterpret_cast<const float4*>(&Bs[kk][tn]);
#pragma unroll
      for (int i = 0; i < 8; ++i)
#pragma unroll
        for (int j = 0; j < 4; ++j) acc[i][j] = fmaf(a[i], b[j], acc[i][j]);
    }
    __syncthreads();
  }
#pragma unroll
  for (int j = 0; j < 4; ++j) {
    const int n = col0 + tn + j;
    ushort4 u0 = make_ushort4(f2bf(acc[0][j]), f2bf(acc[1][j]), f2bf(acc[2][j]), f2bf(acc[3][j]));
    ushort4 u1 = make_ushort4(f2bf(acc[4][j]), f2bf(acc[5][j]), f2bf(acc[6][j]), f2bf(acc[7][j]));
    *reinterpret_cast<ushort4*>(&CT[(size_t)n * M + row0 + tm]) = u0;
    *reinterpret_cast<ushort4*>(&CT[(size_t)n * M + row0 + tm + 4]) = u1;
  }
}

// ---------------------------------------------------------------------------
// x fp32 -> xh, xl bf16; blocks 0..255 also fill the RoPE cos/sin table.
// ---------------------------------------------------------------------------
__global__ __launch_bounds__(256) void repack_x_hl(const float* __restrict__ x,
                                                   unsigned short* __restrict__ xh,
                                                   unsigned short* __restrict__ xl,
                                                   float2* __restrict__ rtab) {
  int i = (blockIdx.x * 256 + threadIdx.x) * 4;
  float4 v = *reinterpret_cast<const float4*>(&x[i]);
  float f[4] = {v.x, v.y, v.z, v.w};
  unsigned short h[4], l[4];
#pragma unroll
  for (int j = 0; j < 4; ++j) {
    h[j] = f2bf(f[j]);
    l[j] = f2bf(f[j] - bf2f(h[j]));
  }
  *reinterpret_cast<ushort4*>(&xh[i]) = make_ushort4(h[0], h[1], h[2], h[3]);
  *reinterpret_cast<ushort4*>(&xl[i]) = make_ushort4(l[0], l[1], l[2], l[3]);
  if (blockIdx.x < 256) {
    int idx = blockIdx.x * 256 + threadIdx.x;
    int d = idx & 31;
    int s = idx >> 5;
    float inv = 1.0f / powf(10000.0f, (float)d * (1.0f / 32.0f));
    float fr = (float)s * inv;
    rtab[idx] = make_float2(cosf(fr), sinf(fr));
  }
}

// ---------------------------------------------------------------------------
// Fused 4-weight transpose repack (Wq, Wk with lo; Wv, Wo hi-only).
// ---------------------------------------------------------------------------
struct RT4 {
  const float* W[4];
  unsigned short* hiT[4];
  unsigned short* loT[4];
  int has_lo[4];
};

__global__ __launch_bounds__(256) void repack_T4(RT4 a) {
  __shared__ float t[64][65];
  const int wsel = blockIdx.z;
  const float* W = a.W[wsel];
  unsigned short* hiT = a.hiT[wsel];
  unsigned short* loT = a.loT[wsel];
  const int has_lo = a.has_lo[wsel];
  const int k0 = blockIdx.y * 64, n0 = blockIdx.x * 64;
  const int tid = threadIdx.x;
  const int c = tid & 63, rr = tid >> 6;
#pragma unroll
  for (int r = 0; r < 16; ++r) {
    int kr = r * 4 + rr;
    t[kr][c] = W[(size_t)(k0 + kr) * D_DIM + n0 + c];
  }
  __syncthreads();
#pragma unroll
  for (int r = 0; r < 16; ++r) {
    int n = r * 4 + rr;
    float f = t[c][n];
    unsigned short hb = f2bf(f);
    hiT[(size_t)(n0 + n) * D_DIM + k0 + c] = hb;
    if (has_lo) loT[(size_t)(n0 + n) * D_DIM + k0 + c] = f2bf(f - bf2f(hb));
  }
}

// ---------------------------------------------------------------------------
// Chunk means of k (k already roped by gemm_qkvg epilogue).
// ---------------------------------------------------------------------------
__global__ __launch_bounds__(256) void chunk_mean(const float* __restrict__ k,
                                                  float* __restrict__ kg) {
  int idx = blockIdx.x * 256 + threadIdx.x;
  if (idx >= NCH * NH * HD) return;
  int c = idx / (NH * HD);
  int hd = idx % (NH * HD);
  float sum = 0.f;
  for (int t = 0; t < CS; ++t) sum += k[(size_t)(c * CS + t) * (NH * HD) + hd];
  kg[idx] = sum * (1.0f / CS);
}

// ---------------------------------------------------------------------------
// Gate + top-3-past chunk selection (fp32; q already roped).
// ---------------------------------------------------------------------------
__global__ __launch_bounds__(256) void gate_topk(const float* __restrict__ q,
                                                 const float* __restrict__ kg,
                                                 int* __restrict__ amask) {
  int wid = threadIdx.x >> 6;
  int lane = threadIdx.x & 63;
  int s = blockIdx.x * 4 + wid;
  int h = blockIdx.y;
  int myc = s >> 8;
  float qd = q[((size_t)s * NH + h) * HD + lane];
  float g[NCH];
#pragma unroll
  for (int c = 0; c < NCH; ++c) {
    float p = qd * kg[((size_t)c * NH + h) * HD + lane];
#pragma unroll
    for (int off = 32; off; off >>= 1) p += __shfl_xor(p, off);
    g[c] = p;
  }
  int chosen = 0;
#pragma unroll
  for (int pick = 0; pick < 3; ++pick) {
    float best = -INFINITY;
    int bi = -1;
#pragma unroll
    for (int c = 0; c < NCH; ++c) {
      if (c < myc && !((chosen >> c) & 1) && g[c] > best) {
        best = g[c];
        bi = c;
      }
    }
    if (bi >= 0) chosen |= (1 << bi);
  }
  int mask = chosen | (1 << myc);
  if (lane == 0) amask[h * S_LEN + s] = mask;
}

// ---------------------------------------------------------------------------
// K,V fp32 [s][h][d] -> fragment-major bf16 (one kernel, both outputs).
// ---------------------------------------------------------------------------
__global__ __launch_bounds__(256) void repack_kvf(const float* __restrict__ k,
                                                  const float* __restrict__ v,
                                                  unsigned short* __restrict__ khf,
                                                  unsigned short* __restrict__ vhf) {
  __shared__ float tk[64][68];
  __shared__ float tv[64][68];
  const int t = blockIdx.x;
  const int h = blockIdx.y;
  const int tid = threadIdx.x;
  const int t0 = t * 64;
  {
    const int r = tid >> 2, c4 = (tid & 3) * 16;
    const float* sk = &k[((size_t)(t0 + r) * NH + h) * HD + c4];
    const float* sv = &v[((size_t)(t0 + r) * NH + h) * HD + c4];
#pragma unroll
    for (int qd = 0; qd < 4; ++qd) {
      *reinterpret_cast<float4*>(&tk[r][c4 + qd * 4]) =
          *reinterpret_cast<const float4*>(sk + qd * 4);
      *reinterpret_cast<float4*>(&tv[r][c4 + qd * 4]) =
          *reinterpret_cast<const float4*>(sv + qd * 4);
    }
  }
  __syncthreads();
  const int w = tid >> 6, l = tid & 63;
  const int l15 = l & 15, g = l >> 4;
  unsigned short* obk = khf + (((size_t)h * 32 + t) * 8) * 512;
  unsigned short* obv = vhf + (((size_t)h * 32 + t) * 8) * 512;
#pragma unroll
  for (int ff = 0; ff < 2; ++ff) {
    const int f = 2 * w + ff;
    {
      const int st = f >> 1, half = f & 1;
      const float* rp = &tk[st * 16 + l15][g * 8 + half * 32];
      ushort4 u0 = make_ushort4(f2bf(rp[0]), f2bf(rp[1]), f2bf(rp[2]), f2bf(rp[3]));
      ushort4 u1 = make_ushort4(f2bf(rp[4]), f2bf(rp[5]), f2bf(rp[6]), f2bf(rp[7]));
      *reinterpret_cast<ushort4*>(obk + (size_t)f * 512 + l * 8) = u0;
      *reinterpret_cast<ushort4*>(obk + (size_t)f * 512 + l * 8 + 4) = u1;
    }
    {
      const int st = f >> 1, p = f & 1;
      unsigned short u[8];
#pragma unroll
      for (int e = 0; e < 8; ++e) {
        const int cb = 2 * p + (e >> 2);
        const int j = e & 3;
        u[e] = f2bf(tv[st * 16 + 4 * g + j][cb * 16 + l15]);
      }
      *reinterpret_cast<ushort4*>(obv + (size_t)f * 512 + l * 8) =
          make_ushort4(u[0], u[1], u[2], u[3]);
      *reinterpret_cast<ushort4*>(obv + (size_t)f * 512 + l * 8 + 4) =
          make_ushort4(u[4], u[5], u[6], u[7]);
    }
  }
}

// ---------------------------------------------------------------------------
// MFMA flash attention, split-K across 4 waves, fragment-major K/V loads.
// Heavy (high-s) blocks scheduled first to shrink the tail. Fused RMS-norm +
// sigmoid gate epilogue emits bf16 o2h directly.
// ---------------------------------------------------------------------------
__global__ __launch_bounds__(256) void attn_mfma(const float* __restrict__ q,
                                                 const unsigned short* __restrict__ khf,
                                                 const unsigned short* __restrict__ vhf,
                                                 const int* __restrict__ amask,
                                                 const float* __restrict__ gbuf,
                                                 const float* __restrict__ onw,
                                                 unsigned short* __restrict__ o2h) {
  const int B = blockIdx.x;
  const int xcd = B & 7;
  const int jb = B >> 3;
  const int h = xcd + ((jb >> 7) << 3);
  const int s0 = (127 - (jb & 127)) << 4;  // heavy blocks first
  const int tid = threadIdx.x;
  const int wid = tid >> 6;
  const int lane = tid & 63;
  const int l15 = lane & 15, g = lane >> 4;
  const int myS = s0 + l15;
  const int myc = s0 >> 8;
  const int ktm = (s0 & (CS - 1)) >> 6;

  __shared__ float lm[4][16];
  __shared__ float ll[4][16];
  __shared__ float lacc[4][16][64];
  __shared__ float lss[4][16];

  const float* qrow = q + ((size_t)myS * NH + h) * HD;
  bf16x8 qf[2];
#pragma unroll
  for (int hf = 0; hf < 2; ++hf)
#pragma unroll
    for (int jj = 0; jj < 8; ++jj)
      qf[hf][jj] = (short)f2bf(qrow[hf * 32 + g * 8 + jj] * 0.125f);

  int mymask = amask[h * S_LEN + myS];
  int wmask = mymask;
  wmask |= __shfl_xor(wmask, 1);
  wmask |= __shfl_xor(wmask, 2);
  wmask |= __shfl_xor(wmask, 4);
  wmask |= __shfl_xor(wmask, 8);
  const int pmask = wmask & ~(1 << myc);
  const int ntot = (ktm + 1) + 4 * __popc(pmask);

  auto DEC = [&](int j) -> int {
    if (j <= ktm) return ((s0 & ~255) + (j << 6)) | (1 << 16);
    int jj = j - ktm - 1;
    int mm = pmask;
    int drop = jj >> 2;
    for (int b = 0; b < drop; ++b) mm &= mm - 1;
    int c = __ffs(mm) - 1;
    return ((c << 8) + ((jj & 3) << 6)) | (((mymask >> c) & 1) << 16);
  };

  const unsigned short* khh = khf + (((size_t)h * 32) << 12);
  const unsigned short* vhh = vhf + (((size_t)h * 32) << 12);

  bf16x8 kr[4][2];
  auto LOADK = [&](int t0) {
    const unsigned short* tb = khh + ((size_t)(t0 >> 6) << 12) + lane * 8;
#pragma unroll
    for (int f = 0; f < 8; ++f)
      kr[f >> 1][f & 1] = *reinterpret_cast<const bf16x8*>(tb + f * 512);
  };

  float m = -1e30f, lsum = 0.f;
  f32x4 accv[4];
#pragma unroll
  for (int i = 0; i < 4; ++i) accv[i] = (f32x4){0.f, 0.f, 0.f, 0.f};

  if (wid < ntot) LOADK(DEC(wid) & 0xFFFF);

#pragma unroll
  for (int i = 0; i < 8; ++i) {
    const int j = wid + (i << 2);
    if (j < ntot) {
      const int ent = DEC(j);
      const int t0 = ent & 0xFFFF;
      const bool lane_on = (ent >> 16) != 0;
      const bool diag = (j == ktm);

      const unsigned short* vtb = vhh + ((size_t)(t0 >> 6) << 12) + lane * 8;
      bf16x4 vb[4][4];
#pragma unroll
      for (int fp = 0; fp < 8; ++fp) {
        bf16x8 wv = *reinterpret_cast<const bf16x8*>(vtb + fp * 512);
        const int st = fp >> 1, pp = fp & 1;
#pragma unroll
        for (int jj = 0; jj < 4; ++jj) {
          vb[st][2 * pp][jj] = wv[jj];
          vb[st][2 * pp + 1][jj] = wv[4 + jj];
        }
      }

      float p[16];
      __builtin_amdgcn_s_setprio(1);
#pragma unroll
      for (int st = 0; st < 4; ++st) {
        f32x4 d = (f32x4){0.f, 0.f, 0.f, 0.f};
        d = __builtin_amdgcn_mfma_f32_16x16x32_bf16(kr[st][0], qf[0], d, 0, 0, 0);
        d = __builtin_amdgcn_mfma_f32_16x16x32_bf16(kr[st][1], qf[1], d, 0, 0, 0);
#pragma unroll
        for (int r = 0; r < 4; ++r) {
          bool ok = lane_on && (!diag || (t0 + st * 16 + 4 * g + r <= myS));
          p[st * 4 + r] = ok ? d[r] : -1e30f;
        }
      }
      __builtin_amdgcn_s_setprio(0);

      if (j + 4 < ntot) LOADK(DEC(j + 4) & 0xFFFF);

      float mt = -1e30f;
#pragma unroll
      for (int ii = 0; ii < 16; ++ii) mt = fmaxf(mt, p[ii]);
      mt = fmaxf(mt, __shfl_xor(mt, 16));
      mt = fmaxf(mt, __shfl_xor(mt, 32));

      const float mnew = fmaxf(m, mt);
      const float corr = __expf(m - mnew);
      float ps = 0.f;
#pragma unroll
      for (int ii = 0; ii < 16; ++ii) {
        float pv = (p[ii] > -1e29f) ? __expf(p[ii] - mnew) : 0.f;
        p[ii] = pv;
        ps += pv;
      }
      ps += __shfl_xor(ps, 16);
      ps += __shfl_xor(ps, 32);
      lsum = lsum * corr + ps;
      m = mnew;

#pragma unroll
      for (int r = 0; r < 4; ++r) {
        float cr = __shfl(corr, 4 * g + r);
#pragma unroll
        for (int cb = 0; cb < 4; ++cb) accv[cb][r] *= cr;
      }

      __builtin_amdgcn_s_setprio(1);
#pragma unroll
      for (int st = 0; st < 4; ++st) {
        bf16x4 pa;
#pragma unroll
        for (int jj = 0; jj < 4; ++jj) pa[jj] = (short)f2bf(p[st * 4 + jj]);
#pragma unroll
        for (int cb = 0; cb < 4; ++cb)
          accv[cb] = mfma16(pa, vb[st][cb], accv[cb]);
      }
      __builtin_amdgcn_s_setprio(0);
    }
  }

#pragma unroll
  for (int cb = 0; cb < 4; ++cb)
#pragma unroll
    for (int r = 0; r < 4; ++r) lacc[wid][cb * 4 + r][lane] = accv[cb][r];
  if (lane < 16) {
    lm[wid][lane] = m;
    ll[wid][lane] = lsum;
  }
  __syncthreads();

  float outv[4];
#pragma unroll
  for (int r = 0; r < 4; ++r) {
    const int row = 4 * g + r;
    float m0 = lm[0][row], m1 = lm[1][row], m2 = lm[2][row], m3 = lm[3][row];
    float mt = fmaxf(fmaxf(m0, m1), fmaxf(m2, m3));
    float e0 = __expf(m0 - mt), e1 = __expf(m1 - mt);
    float e2 = __expf(m2 - mt), e3 = __expf(m3 - mt);
    float ltot = ll[0][row] * e0 + ll[1][row] * e1 + ll[2][row] * e2 + ll[3][row] * e3;
    float a = lacc[0][wid * 4 + r][lane] * e0 + lacc[1][wid * 4 + r][lane] * e1 +
              lacc[2][wid * 4 + r][lane] * e2 + lacc[3][wid * 4 + r][lane] * e3;
    outv[r] = a / ltot;
  }

  // ---- fused RMS-norm + sigmoid gate ----
  float ssr[4];
#pragma unroll
  for (int r = 0; r < 4; ++r) {
    float ss = outv[r] * outv[r];
#pragma unroll
    for (int off = 1; off < 16; off <<= 1) ss += __shfl_xor(ss, off);
    ssr[r] = ss;
  }
  if (l15 == 0) {
#pragma unroll
    for (int r = 0; r < 4; ++r) lss[wid][4 * g + r] = ssr[r];
  }
  __syncthreads();
  const float wgt = onw[wid * 16 + l15];
#pragma unroll
  for (int r = 0; r < 4; ++r) {
    const int row = 4 * g + r;
    float sstot = lss[0][row] + lss[1][row] + lss[2][row] + lss[3][row];
    float rms = rsqrtf(sstot * (1.0f / HD) + 1e-6f);
    float gv = gbuf[(size_t)(s0 + row) * D_DIM + h * HD + wid * 16 + l15];
    float sig = 1.0f / (1.0f + expf(-gv));
    o2h[(size_t)(s0 + row) * D_DIM + h * HD + wid * 16 + l15] =
        f2bf(outv[r] * rms * wgt * sig);
  }
}

// ---------------------------------------------------------------------------
extern "C" void kernel_launch(void* const* d_in, const int* in_sizes, int n_in,
                              void* d_out, int out_size, void* d_ws, size_t ws_size,
                              hipStream_t stream) {
  const float* x   = (const float*)d_in[0];
  const float* Wq  = (const float*)d_in[1];
  const float* Wk  = (const float*)d_in[2];
  const float* Wv  = (const float*)d_in[3];
  const float* Wo  = (const float*)d_in[4];
  const float* Wg1 = (const float*)d_in[5];
  const float* Wg2 = (const float*)d_in[6];
  const float* onw = (const float*)d_in[7];
  float* out = (float*)d_out;

  const size_t BIG = (size_t)S_LEN * D_DIM;  // 4M elements
  float* q    = (float*)d_ws;
  float* k    = q + BIG;
  float* v    = k + BIG;
  float* gbuf = v + BIG;
  float* kg   = gbuf + BIG;                    // NCH*NH*HD
  int* amask  = (int*)(kg + NCH * NH * HD);    // NH*S
  float2* rtab = (float2*)(amask + NH * S_LEN);  // S*32 float2
  unsigned short* xh  = (unsigned short*)(rtab + S_LEN * 32);
  unsigned short* xl  = xh + BIG;
  unsigned short* whq = xl + BIG;
  unsigned short* wlq = whq + BIG;
  unsigned short* whk = wlq + BIG;
  unsigned short* wlk = whk + BIG;
  unsigned short* whv = wlk + BIG;
  unsigned short* whg = whv + BIG;
  unsigned short* who = whg + BIG;
  unsigned short* khf = who + BIG;
  unsigned short* vhf = khf + BIG;
  unsigned short* o2h = vhf + BIG;

  // Split x into hi/lo bf16 (+ rope table in blocks 0..255)
  repack_x_hl<<<(int)(BIG / 4 / 256), 256, 0, stream>>>(x, xh, xl, rtab);
  // Fused weight repacks: Wq(lo), Wk(lo), Wv, Wo
  {
    RT4 rt;
    rt.W[0] = Wq; rt.hiT[0] = whq; rt.loT[0] = wlq; rt.has_lo[0] = 1;
    rt.W[1] = Wk; rt.hiT[1] = whk; rt.loT[1] = wlk; rt.has_lo[1] = 1;
    rt.W[2] = Wv; rt.hiT[2] = whv; rt.loT[2] = whv; rt.has_lo[2] = 0;
    rt.W[3] = Wo; rt.hiT[3] = who; rt.loT[3] = who; rt.has_lo[3] = 0;
    repack_T4<<<dim3(32, 32, 4), 256, 0, stream>>>(rt);
  }
  // W' = Wg1 @ Wg2 -> whg (bf16 transposed, direct; 512 blocks)
  sgemm_f32T<<<dim3(16, 32), 256, 0, stream>>>(Wg1, Wg2, whg, D_DIM, D_DIM, HD);

  // Fused Q(3) K(3) V(1) G(1) projections + RoPE epilogue on Q,K
  {
    QKVG gg;
    gg.xh = xh; gg.xl = xl;
    gg.wh[0] = whq; gg.wh[1] = whk; gg.wh[2] = whv; gg.wh[3] = whg;
    gg.wl[0] = wlq; gg.wl[1] = wlk; gg.wl[2] = nullptr; gg.wl[3] = nullptr;
    gg.C[0] = q; gg.C[1] = k; gg.C[2] = v; gg.C[3] = gbuf;
    gg.np[0] = 3; gg.np[1] = 3; gg.np[2] = 1; gg.np[3] = 1;
    gg.rtab = rtab;
    gemm_qkvg<<<1024, 256, 0, stream>>>(gg);
  }

  // Chunk means + gating (fp32; q,k already roped)
  chunk_mean<<<(NCH * NH * HD + 255) / 256, 256, 0, stream>>>(k, kg);
  gate_topk<<<dim3(S_LEN / 4, NH), 256, 0, stream>>>(q, kg, amask);
  // Fragment-major K/V repack (fused)
  repack_kvf<<<dim3(S_LEN / 64, NH), 256, 0, stream>>>(k, v, khf, vhf);
  // Attention + fused RMS-norm/sigmoid -> bf16 o2h (heavy blocks first)
  attn_mfma<<<(S_LEN / 16) * NH, 256, 0, stream>>>(q, khf, vhf, amask, gbuf, onw, o2h);
  // out = o2 @ Wo
  {
    G3 g3{{o2h, o2h, o2h}, {who, who, who}, 1};
    gemm_bt<<<(S_LEN / 64) * (D_DIM / 128), 256, 0, stream>>>(g3, out, S_LEN, D_DIM, D_DIM);
  }
}